// Round 1
// 249.197 us; speedup vs baseline: 1.0537x; 1.0537x over previous
//
#include <hip/hip_runtime.h>

#define B_SZ 16384
#define DIN  1024
#define HID  512
#define COMP 64

typedef __bf16 bf16_t;
typedef __bf16 bf16x4 __attribute__((ext_vector_type(4)));
typedef __bf16 bf16x8 __attribute__((ext_vector_type(8)));
typedef float  f32x4  __attribute__((ext_vector_type(4)));

#define MFMA16 __builtin_amdgcn_mfma_f32_16x16x32_bf16

__device__ __forceinline__ void gl2lds16(const void* g, void* l) {
    __builtin_amdgcn_global_load_lds(
        (const __attribute__((address_space(1))) void*)g,
        (__attribute__((address_space(3))) void*)l, 16, 0, 0);
}

// ---------------------------------------------------------------------------
// fused prep (unchanged):
//   [0,1024)      : Wb transpose -> bf16 [512][1024]  (x2 branches)
//   [1024,1088)   : Wc transpose -> bf16 [64][512]    (x2 branches)
//   [1088,1104)   : prepG
//   [1104,3152)   : init f1/f2 with bias bc (atomic accumulation target)
//   [3152,19536)  : convert X fp32 -> bf16 row-major (x2 branches)
// ---------------------------------------------------------------------------
__global__ __launch_bounds__(256) void k_prep(
    const float* __restrict__ Wb1, const float* __restrict__ Wb2,
    bf16_t* __restrict__ wbt1, bf16_t* __restrict__ wbt2,
    const float* __restrict__ Wc1, const float* __restrict__ Wc2,
    bf16_t* __restrict__ wct1, bf16_t* __restrict__ wct2,
    const float* __restrict__ Wf1, const float* __restrict__ bf1v,
    const float* __restrict__ Wf2, const float* __restrict__ bf2v,
    const float* __restrict__ bc1, const float* __restrict__ bc2,
    float* __restrict__ f1, float* __restrict__ f2,
    const float* __restrict__ x1, const float* __restrict__ x2,
    bf16_t* __restrict__ xb1, bf16_t* __restrict__ xb2,
    float* __restrict__ G, float* __restrict__ c)
{
    const int bid = blockIdx.x, tid = threadIdx.x;

    if (bid >= 3152) {                    // X convert (bulk of the grid)
        const int l = bid - 3152;         // 0..16383
        const int z = l >> 13;
        const float* x  = z ? x2  : x1;
        bf16_t*      xb = z ? xb2 : xb1;
        const size_t base = ((size_t)(l & 8191) * 256 + tid) * 8;
        float4 v0 = *reinterpret_cast<const float4*>(x + base);
        float4 v1 = *reinterpret_cast<const float4*>(x + base + 4);
        bf16x8 o;
        o[0] = (bf16_t)v0.x; o[1] = (bf16_t)v0.y;
        o[2] = (bf16_t)v0.z; o[3] = (bf16_t)v0.w;
        o[4] = (bf16_t)v1.x; o[5] = (bf16_t)v1.y;
        o[6] = (bf16_t)v1.z; o[7] = (bf16_t)v1.w;
        *reinterpret_cast<bf16x8*>(xb + base) = o;
        return;
    }

    __shared__ float tile[32][33];
    const int tx = tid & 31, ty = tid >> 5;

    if (bid < 1024) {                     // Wb transpose: K=1024, N=512
        const int z = bid >> 9, t = bid & 511;
        const float* in  = z ? Wb2  : Wb1;
        bf16_t*      out = z ? wbt2 : wbt1;
        const int n0 = (t & 15) * 32, k0 = (t >> 4) * 32;
        #pragma unroll
        for (int i = 0; i < 4; i++)
            tile[ty + i * 8][tx] = in[(size_t)(k0 + ty + i * 8) * HID + n0 + tx];
        __syncthreads();
        #pragma unroll
        for (int i = 0; i < 4; i++)
            out[(size_t)(n0 + ty + i * 8) * DIN + k0 + tx] = (bf16_t)tile[tx][ty + i * 8];
    } else if (bid < 1088) {              // Wc transpose: K=512, N=64
        const int l = bid - 1024;
        const int z = l >> 5, t = l & 31;
        const float* in  = z ? Wc2  : Wc1;
        bf16_t*      out = z ? wct2 : wct1;
        const int n0 = (t & 1) * 32, k0 = (t >> 1) * 32;
        #pragma unroll
        for (int i = 0; i < 4; i++)
            tile[ty + i * 8][tx] = in[(size_t)(k0 + ty + i * 8) * COMP + n0 + tx];
        __syncthreads();
        #pragma unroll
        for (int i = 0; i < 4; i++)
            out[(size_t)(n0 + ty + i * 8) * HID + k0 + tx] = (bf16_t)tile[tx][ty + i * 8];
    } else if (bid < 1104) {              // prepG
        const int i = (bid - 1088) * 256 + tid;   // 0..4095
        float a0 = 0.f, a1 = 0.f;
        #pragma unroll 8
        for (int o = 0; o < 64; o++) {
            float w = Wf1[(size_t)i * 64 + o];
            a0 = fmaf(w, Wf2[o * 2 + 0], a0);
            a1 = fmaf(w, Wf2[o * 2 + 1], a1);
        }
        G[i]        = a0;
        G[4096 + i] = a1;
        if (i < 2) {
            float s = bf2v[i];
            for (int o = 0; o < 64; o++) s = fmaf(bf1v[o], Wf2[o * 2 + i], s);
            c[i] = s;
        }
    } else {                              // F init with bias
        const int l = bid - 1104;         // 0..2047
        const int z = l >> 10;
        const float* bc = z ? bc2 : bc1;
        float*       f  = z ? f2  : f1;
        const int i = (l & 1023) * 256 + tid;
        const int c4 = (i & 15) * 4;
        float4 v = make_float4(bc[c4], bc[c4 + 1], bc[c4 + 2], bc[c4 + 3]);
        reinterpret_cast<float4*>(f)[i] = v;
    }
}

// ---------------------------------------------------------------------------
// GEMM1 fused, 256x256-tile 8-wave phase schedule (T1+T2+T3/T4+T5):
//   - 512 threads = 8 waves (2M x 4N), per-wave 128x64 output, BK=64
//   - 128 KiB double-buffered LDS; 16B-chunk XOR swizzle (chunk ^= row&7)
//     applied on BOTH sides: pre-swizzled global source for global_load_lds
//     (dest stays lane-linear) and the same XOR on ds_read addresses.
//   - 4 phases/K-tile: {ds_read frags || 2x global_load_lds(kt+1) || raw
//     s_barrier || setprio(1) 16xMFMA setprio(0) || s_barrier}. A-loads
//     (HBM latency) issue phases 0-1, B-loads (L2-hot panel) phases 2-3;
//     ONE vmcnt(0) per K-tile at the boundary, covered by >=2 MFMA phases.
//   - grid 256 = 1 block/CU; bijective XCD swizzle so each XCD's 32 CUs
//     share one 512KB B-panel (L2-resident).
//   - epilogue: relu(H+bias) -> Hs[256][264] bf16 (stride 264: rows stay
//     16B-aligned, frag reads 2-way banked), per-wave 32-row second GEMM
//     vs wct, atomic F add (2 contributions/element).
// ---------------------------------------------------------------------------
__global__ __launch_bounds__(512, 2) void k_gemm1f(
    const bf16_t* __restrict__ XB1, const bf16_t* __restrict__ XB2,
    const bf16_t* __restrict__ WT1, const bf16_t* __restrict__ WT2,
    const float* __restrict__ bias1, const float* __restrict__ bias2,
    const bf16_t* __restrict__ WC1, const bf16_t* __restrict__ WC2,
    float* __restrict__ F1, float* __restrict__ F2)
{
    const int bid = blockIdx.x;
    const int nid = (bid & 7) * 32 + (bid >> 3);   // bijective: 256 = 8*32
    const int z   = nid >> 7;                      // branch
    const int nb  = (nid >> 6) & 1;                // N column tile
    const int mb  = nid & 63;                      // M tile

    const bf16_t* XB   = z ? XB2   : XB1;
    const bf16_t* WT   = z ? WT2   : WT1;
    const float*  bias = z ? bias2 : bias1;
    const bf16_t* WC   = z ? WC2   : WC1;
    float*        F    = z ? F2    : F1;

    const int m0 = mb * 256;
    const int n0 = nb * 256;

    // A buffers at 0 / 32K, B buffers at 64K / 96K; epilogue Hs aliases all.
    __shared__ __align__(128) char smem[135168];

    const int tid  = threadIdx.x;
    const int lane = tid & 63;
    const int wave = tid >> 6;
    const int wm   = wave >> 2;      // 0..1
    const int wn   = wave & 3;       // 0..3
    const int l15  = lane & 15;
    const int g4   = lane >> 4;

    // ---- staging constants: chunk c = i*512 + tid; row = i*64 + (tid>>3)
    const int srow = tid >> 3;                    // 0..63
    const int sch  = (tid & 7) ^ (srow & 7);      // swizzled source k-chunk
    const bf16_t* gA = XB + (size_t)(m0 + srow) * DIN + sch * 8;
    const bf16_t* gB = WT + (size_t)(n0 + srow) * DIN + sch * 8;
    const int ldst = tid * 16;                    // lane-linear LDS dest

    // ---- fragment-read constants (row&7 == l15&7 since bases are mult of 8)
    const int l7   = l15 & 7;
    const int lch0 = (g4 ^ l7) * 16;              // k-chunk bytes, u=0
    const int lch1 = ((4 + g4) ^ l7) * 16;        // u=1
    const int arow = (wm * 128 + l15) * 128;      // byte base of A row
    const int brow = (wn * 64  + l15) * 128;      // byte base of B row

    f32x4 acc[8][4] = {};

    // ---- prologue: stage K-tile 0 into buffer 0, single cold drain
    #pragma unroll
    for (int i = 0; i < 4; i++) {
        gl2lds16(gA + (size_t)(i * 64) * DIN, smem + i * 8192 + ldst);
        gl2lds16(gB + (size_t)(i * 64) * DIN, smem + 65536 + i * 8192 + ldst);
    }
    asm volatile("s_waitcnt vmcnt(0)" ::: "memory");
    __builtin_amdgcn_s_barrier();
    __builtin_amdgcn_sched_barrier(0);

    bf16x8 a[4][2], b[4][2];

    #pragma unroll 1
    for (int kt = 0; kt < 16; ++kt) {
        const int d = kt & 1;
        const char* Ac = smem + d * 32768;
        const char* Bc = smem + 65536 + d * 32768;
        char* An = (char*)smem + (d ^ 1) * 32768;
        char* Bn = (char*)smem + 65536 + (d ^ 1) * 32768;
        const bf16_t* gAn = gA + (kt + 1) * 64;
        const bf16_t* gBn = gB + (kt + 1) * 64;
        const bool pf = (kt < 15);

        // ================= phase 0: A rows 0-63 frags, B cols 0-31 frags
        #pragma unroll
        for (int mi = 0; mi < 4; mi++) {
            a[mi][0] = *(const bf16x8*)(Ac + arow + mi * 2048 + lch0);
            a[mi][1] = *(const bf16x8*)(Ac + arow + mi * 2048 + lch1);
        }
        #pragma unroll
        for (int ni = 0; ni < 2; ni++) {
            b[ni][0] = *(const bf16x8*)(Bc + brow + ni * 2048 + lch0);
            b[ni][1] = *(const bf16x8*)(Bc + brow + ni * 2048 + lch1);
        }
        if (pf) {                                  // stage next A half 0
            gl2lds16(gAn,                     An + ldst);
            gl2lds16(gAn + (size_t)64 * DIN,  An + 8192 + ldst);
        }
        __builtin_amdgcn_s_barrier();
        __builtin_amdgcn_sched_barrier(0);
        __builtin_amdgcn_s_setprio(1);
        #pragma unroll
        for (int mi = 0; mi < 4; mi++)
            #pragma unroll
            for (int ni = 0; ni < 2; ni++) {
                acc[mi][ni] = MFMA16(a[mi][0], b[ni][0], acc[mi][ni], 0, 0, 0);
                acc[mi][ni] = MFMA16(a[mi][1], b[ni][1], acc[mi][ni], 0, 0, 0);
            }
        __builtin_amdgcn_s_setprio(0);
        __builtin_amdgcn_s_barrier();
        __builtin_amdgcn_sched_barrier(0);

        // ================= phase 1: B cols 32-63 frags
        #pragma unroll
        for (int ni = 2; ni < 4; ni++) {
            b[ni][0] = *(const bf16x8*)(Bc + brow + ni * 2048 + lch0);
            b[ni][1] = *(const bf16x8*)(Bc + brow + ni * 2048 + lch1);
        }
        if (pf) {                                  // stage next A half 1
            gl2lds16(gAn + (size_t)128 * DIN, An + 16384 + ldst);
            gl2lds16(gAn + (size_t)192 * DIN, An + 24576 + ldst);
        }
        __builtin_amdgcn_s_barrier();
        __builtin_amdgcn_sched_barrier(0);
        __builtin_amdgcn_s_setprio(1);
        #pragma unroll
        for (int mi = 0; mi < 4; mi++)
            #pragma unroll
            for (int ni = 2; ni < 4; ni++) {
                acc[mi][ni] = MFMA16(a[mi][0], b[ni][0], acc[mi][ni], 0, 0, 0);
                acc[mi][ni] = MFMA16(a[mi][1], b[ni][1], acc[mi][ni], 0, 0, 0);
            }
        __builtin_amdgcn_s_setprio(0);
        __builtin_amdgcn_s_barrier();
        __builtin_amdgcn_sched_barrier(0);

        // ================= phase 2: A rows 64-127 frags
        #pragma unroll
        for (int mi = 0; mi < 4; mi++) {
            a[mi][0] = *(const bf16x8*)(Ac + arow + 8192 + mi * 2048 + lch0);
            a[mi][1] = *(const bf16x8*)(Ac + arow + 8192 + mi * 2048 + lch1);
        }
        if (pf) {                                  // stage next B half 0
            gl2lds16(gBn,                     Bn + ldst);
            gl2lds16(gBn + (size_t)64 * DIN,  Bn + 8192 + ldst);
        }
        __builtin_amdgcn_s_barrier();
        __builtin_amdgcn_sched_barrier(0);
        __builtin_amdgcn_s_setprio(1);
        #pragma unroll
        for (int mi = 0; mi < 4; mi++)
            #pragma unroll
            for (int ni = 0; ni < 2; ni++) {
                acc[4 + mi][ni] = MFMA16(a[mi][0], b[ni][0], acc[4 + mi][ni], 0, 0, 0);
                acc[4 + mi][ni] = MFMA16(a[mi][1], b[ni][1], acc[4 + mi][ni], 0, 0, 0);
            }
        __builtin_amdgcn_s_setprio(0);
        __builtin_amdgcn_s_barrier();
        __builtin_amdgcn_sched_barrier(0);

        // ================= phase 3: no new frags (regs live)
        if (pf) {                                  // stage next B half 1
            gl2lds16(gBn + (size_t)128 * DIN, Bn + 16384 + ldst);
            gl2lds16(gBn + (size_t)192 * DIN, Bn + 24576 + ldst);
        }
        __builtin_amdgcn_s_barrier();
        __builtin_amdgcn_sched_barrier(0);
        __builtin_amdgcn_s_setprio(1);
        #pragma unroll
        for (int mi = 0; mi < 4; mi++)
            #pragma unroll
            for (int ni = 2; ni < 4; ni++) {
                acc[4 + mi][ni] = MFMA16(a[mi][0], b[ni][0], acc[4 + mi][ni], 0, 0, 0);
                acc[4 + mi][ni] = MFMA16(a[mi][1], b[ni][1], acc[4 + mi][ni], 0, 0, 0);
            }
        __builtin_amdgcn_s_setprio(0);
        // ---- K-tile boundary: the ONLY vmcnt drain, covered by >=2 phases
        if (pf) asm volatile("s_waitcnt vmcnt(0)" ::: "memory");
        __builtin_amdgcn_s_barrier();
        __builtin_amdgcn_sched_barrier(0);
    }

    // ---- epilogue phase 1: Hs[256][264] = relu(H + bias)  (aliases smem)
    bf16_t* Hs = (bf16_t*)smem;
    float bv[4];
    #pragma unroll
    for (int ni = 0; ni < 4; ni++)
        bv[ni] = bias[n0 + wn * 64 + ni * 16 + l15];
    #pragma unroll
    for (int mi = 0; mi < 8; mi++) {
        const int lr = wm * 128 + mi * 16 + g4 * 4;
        #pragma unroll
        for (int ni = 0; ni < 4; ni++) {
            const int colL = wn * 64 + ni * 16 + l15;
            #pragma unroll
            for (int r = 0; r < 4; r++) {
                float v = fmaxf(acc[mi][ni][r] + bv[ni], 0.0f);
                Hs[(lr + r) * 264 + colL] = (bf16_t)v;
            }
        }
    }
    __syncthreads();

    // ---- epilogue phase 2: each wave F[32 rows][64] += Hs-slice @ wct
    f32x4 acc2[2][4] = {};
    #pragma unroll
    for (int kk = 0; kk < 256; kk += 32) {
        bf16x8 af2[2];
        #pragma unroll
        for (int m2 = 0; m2 < 2; m2++)
            af2[m2] = *(const bf16x8*)(Hs + (wave * 32 + m2 * 16 + l15) * 264 + kk + g4 * 8);
        #pragma unroll
        for (int ni = 0; ni < 4; ni++) {
            bf16x8 bw = *(const bf16x8*)(&WC[(size_t)(ni * 16 + l15) * HID + n0 + kk + g4 * 8]);
            #pragma unroll
            for (int m2 = 0; m2 < 2; m2++)
                acc2[m2][ni] = MFMA16(af2[m2], bw, acc2[m2][ni], 0, 0, 0);
        }
    }
    #pragma unroll
    for (int m2 = 0; m2 < 2; m2++) {
        const int rbase = m0 + wave * 32 + m2 * 16 + g4 * 4;
        #pragma unroll
        for (int ni = 0; ni < 4; ni++) {
            const int col = ni * 16 + l15;
            #pragma unroll
            for (int r = 0; r < 4; r++)
                unsafeAtomicAdd(&F[(size_t)(rbase + r) * COMP + col], acc2[m2][ni][r]);
        }
    }
}

// ---------------------------------------------------------------------------
// bilinear: out[b][j] = f2[b] . G_j . f1[b]^T + c[j]
// ---------------------------------------------------------------------------
__global__ __launch_bounds__(256) void k_bilinear(
    const float* __restrict__ f1, const float* __restrict__ f2,
    const float* __restrict__ G, const float* __restrict__ c,
    float* __restrict__ out)
{
    __shared__ float Gs[2][4096];
    const int tid = threadIdx.x;
    for (int i = tid; i < 2048; i += 256)
        reinterpret_cast<float4*>(&Gs[0][0])[i] =
            reinterpret_cast<const float4*>(G)[i];
    const float c0 = c[0], c1 = c[1];
    __syncthreads();

    const int lane = tid & 63;
    const int wave = tid >> 6;
    const int base = (blockIdx.x * 4 + wave) * 4;

    for (int s = 0; s < 4; s++) {
        const int b = base + s;
        const float f1q = f1[(size_t)b * 64 + lane];
        const float f2q = f2[(size_t)b * 64 + lane];
        float a0 = 0.f, a1 = 0.f;
        #pragma unroll 8
        for (int p = 0; p < 64; p++) {
            float s2 = __shfl(f2q, p);
            a0 = fmaf(s2, Gs[0][p * 64 + lane], a0);
            a1 = fmaf(s2, Gs[1][p * 64 + lane], a1);
        }
        a0 *= f1q;
        a1 *= f1q;
        #pragma unroll
        for (int off = 32; off > 0; off >>= 1) {
            a0 += __shfl_xor(a0, off);
            a1 += __shfl_xor(a1, off);
        }
        if (lane == 0) {
            out[(size_t)b * 2 + 0] = a0 + c0;
            out[(size_t)b * 2 + 1] = a1 + c1;
        }
    }
}

// ---------------------------------------------------------------------------
extern "C" void kernel_launch(void* const* d_in, const int* in_sizes, int n_in,
                              void* d_out, int out_size, void* d_ws, size_t ws_size,
                              hipStream_t stream)
{
    const float* x1  = (const float*)d_in[0];
    const float* x2  = (const float*)d_in[1];
    const float* Wb1 = (const float*)d_in[2];
    const float* bb1 = (const float*)d_in[3];
    const float* Wb2 = (const float*)d_in[4];
    const float* bb2 = (const float*)d_in[5];
    const float* Wc1 = (const float*)d_in[6];
    const float* bc1 = (const float*)d_in[7];
    const float* Wc2 = (const float*)d_in[8];
    const float* bc2 = (const float*)d_in[9];
    const float* Wf1 = (const float*)d_in[10];
    const float* bf1v = (const float*)d_in[11];
    const float* Wf2 = (const float*)d_in[12];
    const float* bf2v = (const float*)d_in[13];
    float* out = (float*)d_out;

    // workspace carve-up (~74.8 MB)
    char* ws = (char*)d_ws;
    bf16_t* wbt1 = (bf16_t*)ws; ws += (size_t)HID * DIN * 2;
    bf16_t* wbt2 = (bf16_t*)ws; ws += (size_t)HID * DIN * 2;
    bf16_t* wct1 = (bf16_t*)ws; ws += (size_t)COMP * HID * 2;
    bf16_t* wct2 = (bf16_t*)ws; ws += (size_t)COMP * HID * 2;
    bf16_t* xb1  = (bf16_t*)ws; ws += (size_t)B_SZ * DIN * 2;   // 32 MB
    bf16_t* xb2  = (bf16_t*)ws; ws += (size_t)B_SZ * DIN * 2;   // 32 MB
    float*  f1   = (float*)ws;  ws += (size_t)B_SZ * COMP * 4;
    float*  f2   = (float*)ws;  ws += (size_t)B_SZ * COMP * 4;
    float*  G    = (float*)ws;  ws += (size_t)2 * 4096 * 4;
    float*  c    = (float*)ws;  ws += 256;

    k_prep<<<19536, 256, 0, stream>>>(Wb1, Wb2, wbt1, wbt2,
                                      Wc1, Wc2, wct1, wct2,
                                      Wf1, bf1v, Wf2, bf2v,
                                      bc1, bc2, f1, f2,
                                      x1, x2, xb1, xb2, G, c);
    k_gemm1f<<<256, 512, 0, stream>>>(xb1, xb2, wbt1, wbt2, bb1, bb2,
                                      wct1, wct2, f1, f2);
    k_bilinear<<<1024, 256, 0, stream>>>(f1, f2, G, c, out);
}

// Round 2
// 246.017 us; speedup vs baseline: 1.0674x; 1.0129x over previous
//
#include <hip/hip_runtime.h>

#define B_SZ 16384
#define DIN  1024
#define HID  512
#define COMP 64

typedef __bf16 bf16_t;
typedef __bf16 bf16x4 __attribute__((ext_vector_type(4)));
typedef __bf16 bf16x8 __attribute__((ext_vector_type(8)));
typedef float  f32x4  __attribute__((ext_vector_type(4)));

#define MFMA16 __builtin_amdgcn_mfma_f32_16x16x32_bf16

__device__ __forceinline__ void gl2lds16(const void* g, void* l) {
    __builtin_amdgcn_global_load_lds(
        (const __attribute__((address_space(1))) void*)g,
        (__attribute__((address_space(3))) void*)l, 16, 0, 0);
}

// ---------------------------------------------------------------------------
// fused prep (unchanged):
//   [0,1024)      : Wb transpose -> bf16 [512][1024]  (x2 branches)
//   [1024,1088)   : Wc transpose -> bf16 [64][512]    (x2 branches)
//   [1088,1104)   : prepG
//   [1104,3152)   : init f1/f2 with bias bc (atomic accumulation target)
//   [3152,19536)  : convert X fp32 -> bf16 row-major (x2 branches)
// ---------------------------------------------------------------------------
__global__ __launch_bounds__(256) void k_prep(
    const float* __restrict__ Wb1, const float* __restrict__ Wb2,
    bf16_t* __restrict__ wbt1, bf16_t* __restrict__ wbt2,
    const float* __restrict__ Wc1, const float* __restrict__ Wc2,
    bf16_t* __restrict__ wct1, bf16_t* __restrict__ wct2,
    const float* __restrict__ Wf1, const float* __restrict__ bf1v,
    const float* __restrict__ Wf2, const float* __restrict__ bf2v,
    const float* __restrict__ bc1, const float* __restrict__ bc2,
    float* __restrict__ f1, float* __restrict__ f2,
    const float* __restrict__ x1, const float* __restrict__ x2,
    bf16_t* __restrict__ xb1, bf16_t* __restrict__ xb2,
    float* __restrict__ G, float* __restrict__ c)
{
    const int bid = blockIdx.x, tid = threadIdx.x;

    if (bid >= 3152) {                    // X convert (bulk of the grid)
        const int l = bid - 3152;         // 0..16383
        const int z = l >> 13;
        const float* x  = z ? x2  : x1;
        bf16_t*      xb = z ? xb2 : xb1;
        const size_t base = ((size_t)(l & 8191) * 256 + tid) * 8;
        float4 v0 = *reinterpret_cast<const float4*>(x + base);
        float4 v1 = *reinterpret_cast<const float4*>(x + base + 4);
        bf16x8 o;
        o[0] = (bf16_t)v0.x; o[1] = (bf16_t)v0.y;
        o[2] = (bf16_t)v0.z; o[3] = (bf16_t)v0.w;
        o[4] = (bf16_t)v1.x; o[5] = (bf16_t)v1.y;
        o[6] = (bf16_t)v1.z; o[7] = (bf16_t)v1.w;
        *reinterpret_cast<bf16x8*>(xb + base) = o;
        return;
    }

    __shared__ float tile[32][33];
    const int tx = tid & 31, ty = tid >> 5;

    if (bid < 1024) {                     // Wb transpose: K=1024, N=512
        const int z = bid >> 9, t = bid & 511;
        const float* in  = z ? Wb2  : Wb1;
        bf16_t*      out = z ? wbt2 : wbt1;
        const int n0 = (t & 15) * 32, k0 = (t >> 4) * 32;
        #pragma unroll
        for (int i = 0; i < 4; i++)
            tile[ty + i * 8][tx] = in[(size_t)(k0 + ty + i * 8) * HID + n0 + tx];
        __syncthreads();
        #pragma unroll
        for (int i = 0; i < 4; i++)
            out[(size_t)(n0 + ty + i * 8) * DIN + k0 + tx] = (bf16_t)tile[tx][ty + i * 8];
    } else if (bid < 1088) {              // Wc transpose: K=512, N=64
        const int l = bid - 1024;
        const int z = l >> 5, t = l & 31;
        const float* in  = z ? Wc2  : Wc1;
        bf16_t*      out = z ? wct2 : wct1;
        const int n0 = (t & 1) * 32, k0 = (t >> 1) * 32;
        #pragma unroll
        for (int i = 0; i < 4; i++)
            tile[ty + i * 8][tx] = in[(size_t)(k0 + ty + i * 8) * COMP + n0 + tx];
        __syncthreads();
        #pragma unroll
        for (int i = 0; i < 4; i++)
            out[(size_t)(n0 + ty + i * 8) * HID + k0 + tx] = (bf16_t)tile[tx][ty + i * 8];
    } else if (bid < 1104) {              // prepG
        const int i = (bid - 1088) * 256 + tid;   // 0..4095
        float a0 = 0.f, a1 = 0.f;
        #pragma unroll 8
        for (int o = 0; o < 64; o++) {
            float w = Wf1[(size_t)i * 64 + o];
            a0 = fmaf(w, Wf2[o * 2 + 0], a0);
            a1 = fmaf(w, Wf2[o * 2 + 1], a1);
        }
        G[i]        = a0;
        G[4096 + i] = a1;
        if (i < 2) {
            float s = bf2v[i];
            for (int o = 0; o < 64; o++) s = fmaf(bf1v[o], Wf2[o * 2 + i], s);
            c[i] = s;
        }
    } else {                              // F init with bias
        const int l = bid - 1104;         // 0..2047
        const int z = l >> 10;
        const float* bc = z ? bc2 : bc1;
        float*       f  = z ? f2  : f1;
        const int i = (l & 1023) * 256 + tid;
        const int c4 = (i & 15) * 4;
        float4 v = make_float4(bc[c4], bc[c4 + 1], bc[c4 + 2], bc[c4 + 3]);
        reinterpret_cast<float4*>(f)[i] = v;
    }
}

// ---------------------------------------------------------------------------
// GEMM1 fused — 256x256 tile, BK=64, 8 waves (2M x 4N), counted-vmcnt
// half-granularity pipeline (T4 proper):
//   phase = C-row-half. A staged in ROW-halves (die per phase), B staged as
//   full tiles (die per tile). 3-bit k-chunk XOR swizzle unchanged (A halves
//   are row-ranges, orthogonal to the chunk XOR).
//   kt.p0: issue Ah1(kt+1)+B(kt+1) [6] -> vmcnt(8) (drains tile-kt halves
//          issued 2-3 phases earlier) -> barrier -> 16 ds_reads (a-h0 + all
//          b; b stays in regs for p1) -> 32 MFMA.
//   kt.p1: issue Ah0(kt+2) [2], NO wait -> 8 ds_reads (a-h1) -> 32 MFMA.
//   Loop is fully uniform: tail iterations issue stray (dead-slot, in-bounds)
//   loads so the vmcnt immediate is constant. Single vmcnt(0) after the loop.
//   Issue-to-wait cover ~2-3 phases (~800-1200 cyc) vs HBM ~900.
// ---------------------------------------------------------------------------
__global__ __launch_bounds__(512, 2) void k_gemm1f(
    const bf16_t* __restrict__ XB1, const bf16_t* __restrict__ XB2,
    const bf16_t* __restrict__ WT1, const bf16_t* __restrict__ WT2,
    const float* __restrict__ bias1, const float* __restrict__ bias2,
    const bf16_t* __restrict__ WC1, const bf16_t* __restrict__ WC2,
    float* __restrict__ F1, float* __restrict__ F2)
{
    const int bid = blockIdx.x;
    const int nid = (bid & 7) * 32 + (bid >> 3);   // bijective: 256 = 8*32
    const int z   = nid >> 7;                      // branch
    const int nb  = (nid >> 6) & 1;                // N column tile
    const int mb  = nid & 63;                      // M tile

    const bf16_t* XB   = z ? XB2   : XB1;
    const bf16_t* WT   = z ? WT2   : WT1;
    const float*  bias = z ? bias2 : bias1;
    const bf16_t* WC   = z ? WC2   : WC1;
    float*        F    = z ? F2    : F1;

    const int m0 = mb * 256;
    const int n0 = nb * 256;

    // A slots at 0 / 32K (each: h0 = rows 0-127 at +0, h1 at +16K),
    // B slots at 64K / 96K. Epilogue Hs[256][264] aliases everything.
    __shared__ __align__(128) char smem[135168];

    const int tid  = threadIdx.x;
    const int lane = tid & 63;
    const int wave = tid >> 6;
    const int wm   = wave >> 2;      // 0..1
    const int wn   = wave & 3;       // 0..3
    const int l15  = lane & 15;
    const int g4   = lane >> 4;

    // ---- staging constants (64-row unit): row = j*64 + (tid>>3)
    const int srow = tid >> 3;                    // 0..63
    const int sch  = (tid & 7) ^ (srow & 7);      // swizzled source k-chunk
    const bf16_t* gA = XB + (size_t)(m0 + srow) * DIN + sch * 8;
    const bf16_t* gB = WT + (size_t)(n0 + srow) * DIN + sch * 8;
    const int ldst = tid * 16;                    // lane-linear LDS dest

    // ---- fragment-read constants (row&7 == l15&7: row bases are mult of 8)
    const int l7   = l15 & 7;
    const int lch0 = (g4 ^ l7) * 16;              // k-chunks 0-3 (u=0)
    const int lch1 = ((4 + g4) ^ l7) * 16;        // k-chunks 4-7 (u=1)
    const int abase = (wm * 64 + l15) * 128;      // A row byte base in half
    const int bbase = (wn * 64 + l15) * 128;      // B row byte base

    f32x4 acc[2][4][4] = {};                      // [phase(row-half)][mi][ni]

    // ---- prologue: issue 10 loads in steady-state FIFO order
    // batch "(-2).p1": Ah0(0)
    gl2lds16(gA,                        smem + ldst);
    gl2lds16(gA + (size_t)64 * DIN,     smem + 8192 + ldst);
    // batch "(-1).p0": Ah1(0) + B(0)
    gl2lds16(gA + (size_t)128 * DIN,    smem + 16384 + ldst);
    gl2lds16(gA + (size_t)192 * DIN,    smem + 24576 + ldst);
    gl2lds16(gB,                        smem + 65536 + ldst);
    gl2lds16(gB + (size_t)64 * DIN,     smem + 65536 + 8192 + ldst);
    gl2lds16(gB + (size_t)128 * DIN,    smem + 65536 + 16384 + ldst);
    gl2lds16(gB + (size_t)192 * DIN,    smem + 65536 + 24576 + ldst);
    // batch "(-1).p1": Ah0(1)
    gl2lds16(gA + 64,                   smem + 32768 + ldst);
    gl2lds16(gA + 64 + (size_t)64 * DIN, smem + 32768 + 8192 + ldst);
    __builtin_amdgcn_sched_barrier(0);

    #pragma unroll 1
    for (int kt = 0; kt < 16; ++kt) {
        const int d = kt & 1;
        const char* Ac = smem + d * 32768;
        const char* Bc = smem + 65536 + d * 32768;
        char* An = (char*)smem + (d ^ 1) * 32768;           // slot of kt+1
        char* Bn = (char*)smem + 65536 + (d ^ 1) * 32768;   // slot of kt+1
        char* An2 = (char*)smem + d * 32768;                // slot of kt+2
        const bf16_t* gA1 = gA + (kt + 1) * 64;
        const bf16_t* gA2 = gA + (kt + 2) * 64;
        const bf16_t* gB1 = gB + (kt + 1) * 64;

        // ================= phase 0: C rows 0-127 of tile (A-h0 + all B)
        // stage Ah1(kt+1) [2] + B(kt+1) [4]  (targets dead since kt-1.p1)
        gl2lds16(gA1 + (size_t)128 * DIN, An + 16384 + ldst);
        gl2lds16(gA1 + (size_t)192 * DIN, An + 24576 + ldst);
        gl2lds16(gB1,                     Bn + ldst);
        gl2lds16(gB1 + (size_t)64 * DIN,  Bn + 8192 + ldst);
        gl2lds16(gB1 + (size_t)128 * DIN, Bn + 16384 + ldst);
        gl2lds16(gB1 + (size_t)192 * DIN, Bn + 24576 + ldst);
        __builtin_amdgcn_sched_barrier(0);
        // counted wait: drains Ah0(kt)+Ah1(kt)+B(kt), issued 2-3 phases ago
        asm volatile("s_waitcnt vmcnt(8)" ::: "memory");
        __builtin_amdgcn_s_barrier();
        __builtin_amdgcn_sched_barrier(0);

        bf16x8 a[4][2], b[4][2];
        #pragma unroll
        for (int mi = 0; mi < 4; mi++) {
            a[mi][0] = *(const bf16x8*)(Ac + abase + mi * 2048 + lch0);
            a[mi][1] = *(const bf16x8*)(Ac + abase + mi * 2048 + lch1);
        }
        #pragma unroll
        for (int ni = 0; ni < 4; ni++) {
            b[ni][0] = *(const bf16x8*)(Bc + bbase + ni * 2048 + lch0);
            b[ni][1] = *(const bf16x8*)(Bc + bbase + ni * 2048 + lch1);
        }
        __builtin_amdgcn_s_setprio(1);
        #pragma unroll
        for (int mi = 0; mi < 4; mi++)
            #pragma unroll
            for (int ni = 0; ni < 4; ni++) {
                acc[0][mi][ni] = MFMA16(a[mi][0], b[ni][0], acc[0][mi][ni], 0, 0, 0);
                acc[0][mi][ni] = MFMA16(a[mi][1], b[ni][1], acc[0][mi][ni], 0, 0, 0);
            }
        __builtin_amdgcn_s_setprio(0);
        __builtin_amdgcn_sched_barrier(0);
        __builtin_amdgcn_s_barrier();
        __builtin_amdgcn_sched_barrier(0);

        // ================= phase 1: C rows 128-255 (A-h1; b frags live)
        // stage Ah0(kt+2) [2] (target = this slot's h0, read finished in p0)
        gl2lds16(gA2,                     An2 + ldst);
        gl2lds16(gA2 + (size_t)64 * DIN,  An2 + 8192 + ldst);
        __builtin_amdgcn_sched_barrier(0);
        // no wait: everything needed was drained at p0

        bf16x8 a2[4][2];
        #pragma unroll
        for (int mi = 0; mi < 4; mi++) {
            a2[mi][0] = *(const bf16x8*)(Ac + 16384 + abase + mi * 2048 + lch0);
            a2[mi][1] = *(const bf16x8*)(Ac + 16384 + abase + mi * 2048 + lch1);
        }
        __builtin_amdgcn_s_setprio(1);
        #pragma unroll
        for (int mi = 0; mi < 4; mi++)
            #pragma unroll
            for (int ni = 0; ni < 4; ni++) {
                acc[1][mi][ni] = MFMA16(a2[mi][0], b[ni][0], acc[1][mi][ni], 0, 0, 0);
                acc[1][mi][ni] = MFMA16(a2[mi][1], b[ni][1], acc[1][mi][ni], 0, 0, 0);
            }
        __builtin_amdgcn_s_setprio(0);
        __builtin_amdgcn_sched_barrier(0);
        __builtin_amdgcn_s_barrier();
        __builtin_amdgcn_sched_barrier(0);
    }

    // drain stray tail loads before aliasing smem
    asm volatile("s_waitcnt vmcnt(0)" ::: "memory");
    __builtin_amdgcn_s_barrier();

    // ---- epilogue phase 1: Hs[256][264] = relu(H + bias)  (aliases smem)
    bf16_t* Hs = (bf16_t*)smem;
    float bv[4];
    #pragma unroll
    for (int ni = 0; ni < 4; ni++)
        bv[ni] = bias[n0 + wn * 64 + ni * 16 + l15];
    #pragma unroll
    for (int ph = 0; ph < 2; ph++) {
        #pragma unroll
        for (int mi = 0; mi < 4; mi++) {
            const int lr = ph * 128 + wm * 64 + mi * 16 + g4 * 4;
            #pragma unroll
            for (int ni = 0; ni < 4; ni++) {
                const int colL = wn * 64 + ni * 16 + l15;
                #pragma unroll
                for (int r = 0; r < 4; r++) {
                    float v = fmaxf(acc[ph][mi][ni][r] + bv[ni], 0.0f);
                    Hs[(lr + r) * 264 + colL] = (bf16_t)v;
                }
            }
        }
    }
    __syncthreads();

    // ---- epilogue phase 2: each wave F[32 rows][64] += Hs-slice @ wct
    f32x4 acc2[2][4] = {};
    #pragma unroll
    for (int kk = 0; kk < 256; kk += 32) {
        bf16x8 af2[2];
        #pragma unroll
        for (int m2 = 0; m2 < 2; m2++)
            af2[m2] = *(const bf16x8*)(Hs + (wave * 32 + m2 * 16 + l15) * 264 + kk + g4 * 8);
        #pragma unroll
        for (int ni = 0; ni < 4; ni++) {
            bf16x8 bw = *(const bf16x8*)(&WC[(size_t)(ni * 16 + l15) * HID + n0 + kk + g4 * 8]);
            #pragma unroll
            for (int m2 = 0; m2 < 2; m2++)
                acc2[m2][ni] = MFMA16(af2[m2], bw, acc2[m2][ni], 0, 0, 0);
        }
    }
    #pragma unroll
    for (int m2 = 0; m2 < 2; m2++) {
        const int rbase = m0 + wave * 32 + m2 * 16 + g4 * 4;
        #pragma unroll
        for (int ni = 0; ni < 4; ni++) {
            const int col = ni * 16 + l15;
            #pragma unroll
            for (int r = 0; r < 4; r++)
                unsafeAtomicAdd(&F[(size_t)(rbase + r) * COMP + col], acc2[m2][ni][r]);
        }
    }
}

// ---------------------------------------------------------------------------
// bilinear: out[b][j] = f2[b] . G_j . f1[b]^T + c[j]
// ---------------------------------------------------------------------------
__global__ __launch_bounds__(256) void k_bilinear(
    const float* __restrict__ f1, const float* __restrict__ f2,
    const float* __restrict__ G, const float* __restrict__ c,
    float* __restrict__ out)
{
    __shared__ float Gs[2][4096];
    const int tid = threadIdx.x;
    for (int i = tid; i < 2048; i += 256)
        reinterpret_cast<float4*>(&Gs[0][0])[i] =
            reinterpret_cast<const float4*>(G)[i];
    const float c0 = c[0], c1 = c[1];
    __syncthreads();

    const int lane = tid & 63;
    const int wave = tid >> 6;
    const int base = (blockIdx.x * 4 + wave) * 4;

    for (int s = 0; s < 4; s++) {
        const int b = base + s;
        const float f1q = f1[(size_t)b * 64 + lane];
        const float f2q = f2[(size_t)b * 64 + lane];
        float a0 = 0.f, a1 = 0.f;
        #pragma unroll 8
        for (int p = 0; p < 64; p++) {
            float s2 = __shfl(f2q, p);
            a0 = fmaf(s2, Gs[0][p * 64 + lane], a0);
            a1 = fmaf(s2, Gs[1][p * 64 + lane], a1);
        }
        a0 *= f1q;
        a1 *= f1q;
        #pragma unroll
        for (int off = 32; off > 0; off >>= 1) {
            a0 += __shfl_xor(a0, off);
            a1 += __shfl_xor(a1, off);
        }
        if (lane == 0) {
            out[(size_t)b * 2 + 0] = a0 + c0;
            out[(size_t)b * 2 + 1] = a1 + c1;
        }
    }
}

// ---------------------------------------------------------------------------
extern "C" void kernel_launch(void* const* d_in, const int* in_sizes, int n_in,
                              void* d_out, int out_size, void* d_ws, size_t ws_size,
                              hipStream_t stream)
{
    const float* x1  = (const float*)d_in[0];
    const float* x2  = (const float*)d_in[1];
    const float* Wb1 = (const float*)d_in[2];
    const float* bb1 = (const float*)d_in[3];
    const float* Wb2 = (const float*)d_in[4];
    const float* bb2 = (const float*)d_in[5];
    const float* Wc1 = (const float*)d_in[6];
    const float* bc1 = (const float*)d_in[7];
    const float* Wc2 = (const float*)d_in[8];
    const float* bc2 = (const float*)d_in[9];
    const float* Wf1 = (const float*)d_in[10];
    const float* bf1v = (const float*)d_in[11];
    const float* Wf2 = (const float*)d_in[12];
    const float* bf2v = (const float*)d_in[13];
    float* out = (float*)d_out;

    // workspace carve-up (~74.8 MB)
    char* ws = (char*)d_ws;
    bf16_t* wbt1 = (bf16_t*)ws; ws += (size_t)HID * DIN * 2;
    bf16_t* wbt2 = (bf16_t*)ws; ws += (size_t)HID * DIN * 2;
    bf16_t* wct1 = (bf16_t*)ws; ws += (size_t)COMP * HID * 2;
    bf16_t* wct2 = (bf16_t*)ws; ws += (size_t)COMP * HID * 2;
    bf16_t* xb1  = (bf16_t*)ws; ws += (size_t)B_SZ * DIN * 2;   // 32 MB
    bf16_t* xb2  = (bf16_t*)ws; ws += (size_t)B_SZ * DIN * 2;   // 32 MB
    float*  f1   = (float*)ws;  ws += (size_t)B_SZ * COMP * 4;
    float*  f2   = (float*)ws;  ws += (size_t)B_SZ * COMP * 4;
    float*  G    = (float*)ws;  ws += (size_t)2 * 4096 * 4;
    float*  c    = (float*)ws;  ws += 256;

    k_prep<<<19536, 256, 0, stream>>>(Wb1, Wb2, wbt1, wbt2,
                                      Wc1, Wc2, wct1, wct2,
                                      Wf1, bf1v, Wf2, bf2v,
                                      bc1, bc2, f1, f2,
                                      x1, x2, xb1, xb2, G, c);
    k_gemm1f<<<256, 512, 0, stream>>>(xb1, xb2, wbt1, wbt2, bb1, bb2,
                                      wct1, wct2, f1, f2);
    k_bilinear<<<1024, 256, 0, stream>>>(f1, f2, G, c, out);
}

// Round 3
// 243.736 us; speedup vs baseline: 1.0773x; 1.0094x over previous
//
#include <hip/hip_runtime.h>

#define B_SZ 16384
#define DIN  1024
#define HID  512
#define COMP 64

typedef __bf16 bf16_t;
typedef __bf16 bf16x4 __attribute__((ext_vector_type(4)));
typedef __bf16 bf16x8 __attribute__((ext_vector_type(8)));
typedef float  f32x4  __attribute__((ext_vector_type(4)));

#define MFMA16 __builtin_amdgcn_mfma_f32_16x16x32_bf16

__device__ __forceinline__ void gl2lds16(const void* g, void* l) {
    __builtin_amdgcn_global_load_lds(
        (const __attribute__((address_space(1))) void*)g,
        (__attribute__((address_space(3))) void*)l, 16, 0, 0);
}

// ---------------------------------------------------------------------------
// fused prep:
//   [0,1024)      : Wb transpose -> bf16 [512][1024]  (x2 branches)
//   [1024,1088)   : Wc transpose -> bf16 [64][512]    (x2 branches)
//   [1088,1104)   : prepG
//   [1104,3152)   : init f1/f2 with bias bc (atomic accumulation target)
//   [3152,5200)   : convert X fp32 -> bf16, GRID-STRIDE x8 per thread
//                   (2048 blocks; chunk c = i0 + k*524288, k<4 -> x1,
//                    k>=4 -> x2 exactly since x1 = 4*524288 chunks)
// ---------------------------------------------------------------------------
__global__ __launch_bounds__(256) void k_prep(
    const float* __restrict__ Wb1, const float* __restrict__ Wb2,
    bf16_t* __restrict__ wbt1, bf16_t* __restrict__ wbt2,
    const float* __restrict__ Wc1, const float* __restrict__ Wc2,
    bf16_t* __restrict__ wct1, bf16_t* __restrict__ wct2,
    const float* __restrict__ Wf1, const float* __restrict__ bf1v,
    const float* __restrict__ Wf2, const float* __restrict__ bf2v,
    const float* __restrict__ bc1, const float* __restrict__ bc2,
    float* __restrict__ f1, float* __restrict__ f2,
    const float* __restrict__ x1, const float* __restrict__ x2,
    bf16_t* __restrict__ xb1, bf16_t* __restrict__ xb2,
    float* __restrict__ G, float* __restrict__ c)
{
    const int bid = blockIdx.x, tid = threadIdx.x;

    if (bid >= 3152) {                    // X convert, grid-stride
        const int i0 = (bid - 3152) * 256 + tid;   // 0..524287
        #pragma unroll
        for (int k = 0; k < 8; k++) {
            const float* x  = (k < 4) ? x1  : x2;
            bf16_t*      xb = (k < 4) ? xb2 : xb2; // placeholder, fixed below
            xb = (k < 4) ? xb1 : xb2;
            const size_t ch = (size_t)i0 + (size_t)(k & 3) * 524288;
            const size_t base = ch * 8;
            float4 v0 = *reinterpret_cast<const float4*>(x + base);
            float4 v1 = *reinterpret_cast<const float4*>(x + base + 4);
            bf16x8 o;
            o[0] = (bf16_t)v0.x; o[1] = (bf16_t)v0.y;
            o[2] = (bf16_t)v0.z; o[3] = (bf16_t)v0.w;
            o[4] = (bf16_t)v1.x; o[5] = (bf16_t)v1.y;
            o[6] = (bf16_t)v1.z; o[7] = (bf16_t)v1.w;
            *reinterpret_cast<bf16x8*>(xb + base) = o;
        }
        return;
    }

    __shared__ float tile[32][33];
    const int tx = tid & 31, ty = tid >> 5;

    if (bid < 1024) {                     // Wb transpose: K=1024, N=512
        const int z = bid >> 9, t = bid & 511;
        const float* in  = z ? Wb2  : Wb1;
        bf16_t*      out = z ? wbt2 : wbt1;
        const int n0 = (t & 15) * 32, k0 = (t >> 4) * 32;
        #pragma unroll
        for (int i = 0; i < 4; i++)
            tile[ty + i * 8][tx] = in[(size_t)(k0 + ty + i * 8) * HID + n0 + tx];
        __syncthreads();
        #pragma unroll
        for (int i = 0; i < 4; i++)
            out[(size_t)(n0 + ty + i * 8) * DIN + k0 + tx] = (bf16_t)tile[tx][ty + i * 8];
    } else if (bid < 1088) {              // Wc transpose: K=512, N=64
        const int l = bid - 1024;
        const int z = l >> 5, t = l & 31;
        const float* in  = z ? Wc2  : Wc1;
        bf16_t*      out = z ? wct2 : wct1;
        const int n0 = (t & 1) * 32, k0 = (t >> 1) * 32;
        #pragma unroll
        for (int i = 0; i < 4; i++)
            tile[ty + i * 8][tx] = in[(size_t)(k0 + ty + i * 8) * COMP + n0 + tx];
        __syncthreads();
        #pragma unroll
        for (int i = 0; i < 4; i++)
            out[(size_t)(n0 + ty + i * 8) * HID + k0 + tx] = (bf16_t)tile[tx][ty + i * 8];
    } else if (bid < 1104) {              // prepG
        const int i = (bid - 1088) * 256 + tid;   // 0..4095
        float a0 = 0.f, a1 = 0.f;
        #pragma unroll 8
        for (int o = 0; o < 64; o++) {
            float w = Wf1[(size_t)i * 64 + o];
            a0 = fmaf(w, Wf2[o * 2 + 0], a0);
            a1 = fmaf(w, Wf2[o * 2 + 1], a1);
        }
        G[i]        = a0;
        G[4096 + i] = a1;
        if (i < 2) {
            float s = bf2v[i];
            for (int o = 0; o < 64; o++) s = fmaf(bf1v[o], Wf2[o * 2 + i], s);
            c[i] = s;
        }
    } else {                              // F init with bias
        const int l = bid - 1104;         // 0..2047
        const int z = l >> 10;
        const float* bc = z ? bc2 : bc1;
        float*       f  = z ? f2  : f1;
        const int i = (l & 1023) * 256 + tid;
        const int c4 = (i & 15) * 4;
        float4 v = make_float4(bc[c4], bc[c4 + 1], bc[c4 + 2], bc[c4 + 3]);
        reinterpret_cast<float4*>(f)[i] = v;
    }
}

// ---------------------------------------------------------------------------
// GEMM1 fused — 256x256 tile, BK=64, 8 waves (2M x 4N), counted-vmcnt
// half-granularity pipeline (FROZEN from round 2 to isolate prep/bilinear).
// ---------------------------------------------------------------------------
__global__ __launch_bounds__(512, 2) void k_gemm1f(
    const bf16_t* __restrict__ XB1, const bf16_t* __restrict__ XB2,
    const bf16_t* __restrict__ WT1, const bf16_t* __restrict__ WT2,
    const float* __restrict__ bias1, const float* __restrict__ bias2,
    const bf16_t* __restrict__ WC1, const bf16_t* __restrict__ WC2,
    float* __restrict__ F1, float* __restrict__ F2)
{
    const int bid = blockIdx.x;
    const int nid = (bid & 7) * 32 + (bid >> 3);   // bijective: 256 = 8*32
    const int z   = nid >> 7;                      // branch
    const int nb  = (nid >> 6) & 1;                // N column tile
    const int mb  = nid & 63;                      // M tile

    const bf16_t* XB   = z ? XB2   : XB1;
    const bf16_t* WT   = z ? WT2   : WT1;
    const float*  bias = z ? bias2 : bias1;
    const bf16_t* WC   = z ? WC2   : WC1;
    float*        F    = z ? F2    : F1;

    const int m0 = mb * 256;
    const int n0 = nb * 256;

    __shared__ __align__(128) char smem[135168];

    const int tid  = threadIdx.x;
    const int lane = tid & 63;
    const int wave = tid >> 6;
    const int wm   = wave >> 2;      // 0..1
    const int wn   = wave & 3;       // 0..3
    const int l15  = lane & 15;
    const int g4   = lane >> 4;

    const int srow = tid >> 3;                    // 0..63
    const int sch  = (tid & 7) ^ (srow & 7);      // swizzled source k-chunk
    const bf16_t* gA = XB + (size_t)(m0 + srow) * DIN + sch * 8;
    const bf16_t* gB = WT + (size_t)(n0 + srow) * DIN + sch * 8;
    const int ldst = tid * 16;                    // lane-linear LDS dest

    const int l7   = l15 & 7;
    const int lch0 = (g4 ^ l7) * 16;              // k-chunks 0-3 (u=0)
    const int lch1 = ((4 + g4) ^ l7) * 16;        // k-chunks 4-7 (u=1)
    const int abase = (wm * 64 + l15) * 128;      // A row byte base in half
    const int bbase = (wn * 64 + l15) * 128;      // B row byte base

    f32x4 acc[2][4][4] = {};                      // [phase(row-half)][mi][ni]

    // ---- prologue: issue 10 loads in steady-state FIFO order
    gl2lds16(gA,                        smem + ldst);
    gl2lds16(gA + (size_t)64 * DIN,     smem + 8192 + ldst);
    gl2lds16(gA + (size_t)128 * DIN,    smem + 16384 + ldst);
    gl2lds16(gA + (size_t)192 * DIN,    smem + 24576 + ldst);
    gl2lds16(gB,                        smem + 65536 + ldst);
    gl2lds16(gB + (size_t)64 * DIN,     smem + 65536 + 8192 + ldst);
    gl2lds16(gB + (size_t)128 * DIN,    smem + 65536 + 16384 + ldst);
    gl2lds16(gB + (size_t)192 * DIN,    smem + 65536 + 24576 + ldst);
    gl2lds16(gA + 64,                   smem + 32768 + ldst);
    gl2lds16(gA + 64 + (size_t)64 * DIN, smem + 32768 + 8192 + ldst);
    __builtin_amdgcn_sched_barrier(0);

    #pragma unroll 1
    for (int kt = 0; kt < 16; ++kt) {
        const int d = kt & 1;
        const char* Ac = smem + d * 32768;
        const char* Bc = smem + 65536 + d * 32768;
        char* An = (char*)smem + (d ^ 1) * 32768;           // slot of kt+1
        char* Bn = (char*)smem + 65536 + (d ^ 1) * 32768;   // slot of kt+1
        char* An2 = (char*)smem + d * 32768;                // slot of kt+2
        const bf16_t* gA1 = gA + (kt + 1) * 64;
        const bf16_t* gA2 = gA + (kt + 2) * 64;
        const bf16_t* gB1 = gB + (kt + 1) * 64;

        // ================= phase 0: C rows 0-127 of tile (A-h0 + all B)
        gl2lds16(gA1 + (size_t)128 * DIN, An + 16384 + ldst);
        gl2lds16(gA1 + (size_t)192 * DIN, An + 24576 + ldst);
        gl2lds16(gB1,                     Bn + ldst);
        gl2lds16(gB1 + (size_t)64 * DIN,  Bn + 8192 + ldst);
        gl2lds16(gB1 + (size_t)128 * DIN, Bn + 16384 + ldst);
        gl2lds16(gB1 + (size_t)192 * DIN, Bn + 24576 + ldst);
        __builtin_amdgcn_sched_barrier(0);
        asm volatile("s_waitcnt vmcnt(8)" ::: "memory");
        __builtin_amdgcn_s_barrier();
        __builtin_amdgcn_sched_barrier(0);

        bf16x8 a[4][2], b[4][2];
        #pragma unroll
        for (int mi = 0; mi < 4; mi++) {
            a[mi][0] = *(const bf16x8*)(Ac + abase + mi * 2048 + lch0);
            a[mi][1] = *(const bf16x8*)(Ac + abase + mi * 2048 + lch1);
        }
        #pragma unroll
        for (int ni = 0; ni < 4; ni++) {
            b[ni][0] = *(const bf16x8*)(Bc + bbase + ni * 2048 + lch0);
            b[ni][1] = *(const bf16x8*)(Bc + bbase + ni * 2048 + lch1);
        }
        __builtin_amdgcn_s_setprio(1);
        #pragma unroll
        for (int mi = 0; mi < 4; mi++)
            #pragma unroll
            for (int ni = 0; ni < 4; ni++) {
                acc[0][mi][ni] = MFMA16(a[mi][0], b[ni][0], acc[0][mi][ni], 0, 0, 0);
                acc[0][mi][ni] = MFMA16(a[mi][1], b[ni][1], acc[0][mi][ni], 0, 0, 0);
            }
        __builtin_amdgcn_s_setprio(0);
        __builtin_amdgcn_sched_barrier(0);
        __builtin_amdgcn_s_barrier();
        __builtin_amdgcn_sched_barrier(0);

        // ================= phase 1: C rows 128-255 (A-h1; b frags live)
        gl2lds16(gA2,                     An2 + ldst);
        gl2lds16(gA2 + (size_t)64 * DIN,  An2 + 8192 + ldst);
        __builtin_amdgcn_sched_barrier(0);

        bf16x8 a2[4][2];
        #pragma unroll
        for (int mi = 0; mi < 4; mi++) {
            a2[mi][0] = *(const bf16x8*)(Ac + 16384 + abase + mi * 2048 + lch0);
            a2[mi][1] = *(const bf16x8*)(Ac + 16384 + abase + mi * 2048 + lch1);
        }
        __builtin_amdgcn_s_setprio(1);
        #pragma unroll
        for (int mi = 0; mi < 4; mi++)
            #pragma unroll
            for (int ni = 0; ni < 4; ni++) {
                acc[1][mi][ni] = MFMA16(a2[mi][0], b[ni][0], acc[1][mi][ni], 0, 0, 0);
                acc[1][mi][ni] = MFMA16(a2[mi][1], b[ni][1], acc[1][mi][ni], 0, 0, 0);
            }
        __builtin_amdgcn_s_setprio(0);
        __builtin_amdgcn_sched_barrier(0);
        __builtin_amdgcn_s_barrier();
        __builtin_amdgcn_sched_barrier(0);
    }

    asm volatile("s_waitcnt vmcnt(0)" ::: "memory");
    __builtin_amdgcn_s_barrier();

    // ---- epilogue phase 1: Hs[256][264] = relu(H + bias)  (aliases smem)
    bf16_t* Hs = (bf16_t*)smem;
    float bv[4];
    #pragma unroll
    for (int ni = 0; ni < 4; ni++)
        bv[ni] = bias[n0 + wn * 64 + ni * 16 + l15];
    #pragma unroll
    for (int ph = 0; ph < 2; ph++) {
        #pragma unroll
        for (int mi = 0; mi < 4; mi++) {
            const int lr = ph * 128 + wm * 64 + mi * 16 + g4 * 4;
            #pragma unroll
            for (int ni = 0; ni < 4; ni++) {
                const int colL = wn * 64 + ni * 16 + l15;
                #pragma unroll
                for (int r = 0; r < 4; r++) {
                    float v = fmaxf(acc[ph][mi][ni][r] + bv[ni], 0.0f);
                    Hs[(lr + r) * 264 + colL] = (bf16_t)v;
                }
            }
        }
    }
    __syncthreads();

    // ---- epilogue phase 2: each wave F[32 rows][64] += Hs-slice @ wct
    f32x4 acc2[2][4] = {};
    #pragma unroll
    for (int kk = 0; kk < 256; kk += 32) {
        bf16x8 af2[2];
        #pragma unroll
        for (int m2 = 0; m2 < 2; m2++)
            af2[m2] = *(const bf16x8*)(Hs + (wave * 32 + m2 * 16 + l15) * 264 + kk + g4 * 8);
        #pragma unroll
        for (int ni = 0; ni < 4; ni++) {
            bf16x8 bw = *(const bf16x8*)(&WC[(size_t)(ni * 16 + l15) * HID + n0 + kk + g4 * 8]);
            #pragma unroll
            for (int m2 = 0; m2 < 2; m2++)
                acc2[m2][ni] = MFMA16(af2[m2], bw, acc2[m2][ni], 0, 0, 0);
        }
    }
    #pragma unroll
    for (int m2 = 0; m2 < 2; m2++) {
        const int rbase = m0 + wave * 32 + m2 * 16 + g4 * 4;
        #pragma unroll
        for (int ni = 0; ni < 4; ni++) {
            const int col = ni * 16 + l15;
            #pragma unroll
            for (int r = 0; r < 4; r++)
                unsafeAtomicAdd(&F[(size_t)(rbase + r) * COMP + col], acc2[m2][ni][r]);
        }
    }
}

// ---------------------------------------------------------------------------
// bilinear REBUILT (fp32 throughout, same math):
//   out[b][j] = f2[b,:] . G_j . f1[b,:]^T + c[j]
//   256 blocks x 64 samples. LDS: G (32KB) + transposed f1/f2 tiles
//   (stride 66, conflict-free lane-varying reads). Thread = (sample lane,
//   wv=(j,q-half)); 32 f32 accumulators; G rows read as lane-uniform
//   float4 BROADCASTS (1 LDS op per 4 fma) -> VALU-bound, no shfl loop.
// ---------------------------------------------------------------------------
__global__ __launch_bounds__(256) void k_bilinear(
    const float* __restrict__ f1, const float* __restrict__ f2,
    const float* __restrict__ G, const float* __restrict__ c,
    float* __restrict__ out)
{
    __shared__ float Gs[2][4096];
    __shared__ float f1t[64][66];
    __shared__ float f2t[64][66];
    __shared__ float part[4][64];

    const int tid = threadIdx.x;
    const int s0  = blockIdx.x * 64;

    // stage G: 2048 float4
    for (int i = tid; i < 2048; i += 256)
        reinterpret_cast<float4*>(&Gs[0][0])[i] =
            reinterpret_cast<const float4*>(G)[i];

    // stage f1/f2 tiles transposed: [q][s]
    #pragma unroll
    for (int rr = 0; rr < 4; rr++) {
        const int row = (tid >> 4) + rr * 16;     // sample within tile
        const int c4  = (tid & 15) * 4;
        float4 v1 = *reinterpret_cast<const float4*>(&f1[(size_t)(s0 + row) * 64 + c4]);
        float4 v2 = *reinterpret_cast<const float4*>(&f2[(size_t)(s0 + row) * 64 + c4]);
        f1t[c4 + 0][row] = v1.x; f1t[c4 + 1][row] = v1.y;
        f1t[c4 + 2][row] = v1.z; f1t[c4 + 3][row] = v1.w;
        f2t[c4 + 0][row] = v2.x; f2t[c4 + 1][row] = v2.y;
        f2t[c4 + 2][row] = v2.z; f2t[c4 + 3][row] = v2.w;
    }
    __syncthreads();

    const int lane = tid & 63;        // sample
    const int wv   = tid >> 6;        // 0..3
    const int j    = wv & 1;
    const int qh   = (wv >> 1) * 32;

    float tq[32];
    #pragma unroll
    for (int q = 0; q < 32; q++) tq[q] = 0.f;

    #pragma unroll 4
    for (int p = 0; p < 64; p++) {
        const float f2p = f2t[p][lane];                 // lane-varying, conflict-free
        const float* Gp = &Gs[j][p * 64 + qh];          // lane-uniform
        #pragma unroll
        for (int q4 = 0; q4 < 8; q4++) {
            float4 g = *reinterpret_cast<const float4*>(Gp + q4 * 4);   // broadcast
            tq[q4 * 4 + 0] = fmaf(f2p, g.x, tq[q4 * 4 + 0]);
            tq[q4 * 4 + 1] = fmaf(f2p, g.y, tq[q4 * 4 + 1]);
            tq[q4 * 4 + 2] = fmaf(f2p, g.z, tq[q4 * 4 + 2]);
            tq[q4 * 4 + 3] = fmaf(f2p, g.w, tq[q4 * 4 + 3]);
        }
    }

    float o = 0.f;
    #pragma unroll
    for (int q = 0; q < 32; q++)
        o = fmaf(f1t[qh + q][lane], tq[q], o);

    part[wv][lane] = o;
    __syncthreads();

    if (wv < 2) {
        float r = part[wv][lane] + part[wv + 2][lane] + c[wv];
        out[(size_t)(s0 + lane) * 2 + wv] = r;
    }
}

// ---------------------------------------------------------------------------
extern "C" void kernel_launch(void* const* d_in, const int* in_sizes, int n_in,
                              void* d_out, int out_size, void* d_ws, size_t ws_size,
                              hipStream_t stream)
{
    const float* x1  = (const float*)d_in[0];
    const float* x2  = (const float*)d_in[1];
    const float* Wb1 = (const float*)d_in[2];
    const float* bb1 = (const float*)d_in[3];
    const float* Wb2 = (const float*)d_in[4];
    const float* bb2 = (const float*)d_in[5];
    const float* Wc1 = (const float*)d_in[6];
    const float* bc1 = (const float*)d_in[7];
    const float* Wc2 = (const float*)d_in[8];
    const float* bc2 = (const float*)d_in[9];
    const float* Wf1 = (const float*)d_in[10];
    const float* bf1v = (const float*)d_in[11];
    const float* Wf2 = (const float*)d_in[12];
    const float* bf2v = (const float*)d_in[13];
    float* out = (float*)d_out;

    // workspace carve-up (~74.8 MB)
    char* ws = (char*)d_ws;
    bf16_t* wbt1 = (bf16_t*)ws; ws += (size_t)HID * DIN * 2;
    bf16_t* wbt2 = (bf16_t*)ws; ws += (size_t)HID * DIN * 2;
    bf16_t* wct1 = (bf16_t*)ws; ws += (size_t)COMP * HID * 2;
    bf16_t* wct2 = (bf16_t*)ws; ws += (size_t)COMP * HID * 2;
    bf16_t* xb1  = (bf16_t*)ws; ws += (size_t)B_SZ * DIN * 2;   // 32 MB
    bf16_t* xb2  = (bf16_t*)ws; ws += (size_t)B_SZ * DIN * 2;   // 32 MB
    float*  f1   = (float*)ws;  ws += (size_t)B_SZ * COMP * 4;
    float*  f2   = (float*)ws;  ws += (size_t)B_SZ * COMP * 4;
    float*  G    = (float*)ws;  ws += (size_t)2 * 4096 * 4;
    float*  c    = (float*)ws;  ws += 256;

    k_prep<<<5200, 256, 0, stream>>>(Wb1, Wb2, wbt1, wbt2,
                                     Wc1, Wc2, wct1, wct2,
                                     Wf1, bf1v, Wf2, bf2v,
                                     bc1, bc2, f1, f2,
                                     x1, x2, xb1, xb2, G, c);
    k_gemm1f<<<256, 512, 0, stream>>>(xb1, xb2, wbt1, wbt2, bb1, bb2,
                                      wct1, wct2, f1, f2);
    k_bilinear<<<256, 256, 0, stream>>>(f1, f2, G, c, out);
}

// Round 4
// 224.230 us; speedup vs baseline: 1.1711x; 1.0870x over previous
//
#include <hip/hip_runtime.h>

#define B_SZ 16384
#define DIN  1024
#define HID  512
#define COMP 64

typedef __bf16 bf16_t;
typedef __bf16 bf16x4 __attribute__((ext_vector_type(4)));
typedef __bf16 bf16x8 __attribute__((ext_vector_type(8)));
typedef float  f32x4  __attribute__((ext_vector_type(4)));

#define MFMA16 __builtin_amdgcn_mfma_f32_16x16x32_bf16

__device__ __forceinline__ void gl2lds16(const void* g, void* l) {
    __builtin_amdgcn_global_load_lds(
        (const __attribute__((address_space(1))) void*)g,
        (__attribute__((address_space(3))) void*)l, 16, 0, 0);
}

__device__ __forceinline__ bf16x8 cvt8(float4 a, float4 b) {
    bf16x8 o;
    o[0] = (bf16_t)a.x; o[1] = (bf16_t)a.y;
    o[2] = (bf16_t)a.z; o[3] = (bf16_t)a.w;
    o[4] = (bf16_t)b.x; o[5] = (bf16_t)b.y;
    o[6] = (bf16_t)b.z; o[7] = (bf16_t)b.w;
    return o;
}

// ---------------------------------------------------------------------------
// prep (X-convert REMOVED — conversion fused into gemm A-staging):
//   [0,1024)      : Wb transpose -> bf16 [512][1024]  (x2 branches)
//   [1024,1088)   : Wc transpose -> bf16 [64][512]    (x2 branches)
//   [1088,1104)   : prepG
//   [1104,3152)   : init f1/f2 with bias bc (atomic accumulation target)
// ---------------------------------------------------------------------------
__global__ __launch_bounds__(256) void k_prep(
    const float* __restrict__ Wb1, const float* __restrict__ Wb2,
    bf16_t* __restrict__ wbt1, bf16_t* __restrict__ wbt2,
    const float* __restrict__ Wc1, const float* __restrict__ Wc2,
    bf16_t* __restrict__ wct1, bf16_t* __restrict__ wct2,
    const float* __restrict__ Wf1, const float* __restrict__ bf1v,
    const float* __restrict__ Wf2, const float* __restrict__ bf2v,
    const float* __restrict__ bc1, const float* __restrict__ bc2,
    float* __restrict__ f1, float* __restrict__ f2,
    float* __restrict__ G, float* __restrict__ c)
{
    const int bid = blockIdx.x, tid = threadIdx.x;

    __shared__ float tile[32][33];
    const int tx = tid & 31, ty = tid >> 5;

    if (bid < 1024) {                     // Wb transpose: K=1024, N=512
        const int z = bid >> 9, t = bid & 511;
        const float* in  = z ? Wb2  : Wb1;
        bf16_t*      out = z ? wbt2 : wbt1;
        const int n0 = (t & 15) * 32, k0 = (t >> 4) * 32;
        #pragma unroll
        for (int i = 0; i < 4; i++)
            tile[ty + i * 8][tx] = in[(size_t)(k0 + ty + i * 8) * HID + n0 + tx];
        __syncthreads();
        #pragma unroll
        for (int i = 0; i < 4; i++)
            out[(size_t)(n0 + ty + i * 8) * DIN + k0 + tx] = (bf16_t)tile[tx][ty + i * 8];
    } else if (bid < 1088) {              // Wc transpose: K=512, N=64
        const int l = bid - 1024;
        const int z = l >> 5, t = l & 31;
        const float* in  = z ? Wc2  : Wc1;
        bf16_t*      out = z ? wct2 : wct1;
        const int n0 = (t & 1) * 32, k0 = (t >> 1) * 32;
        #pragma unroll
        for (int i = 0; i < 4; i++)
            tile[ty + i * 8][tx] = in[(size_t)(k0 + ty + i * 8) * COMP + n0 + tx];
        __syncthreads();
        #pragma unroll
        for (int i = 0; i < 4; i++)
            out[(size_t)(n0 + ty + i * 8) * HID + k0 + tx] = (bf16_t)tile[tx][ty + i * 8];
    } else if (bid < 1104) {              // prepG
        const int i = (bid - 1088) * 256 + tid;   // 0..4095
        float a0 = 0.f, a1 = 0.f;
        #pragma unroll 8
        for (int o = 0; o < 64; o++) {
            float w = Wf1[(size_t)i * 64 + o];
            a0 = fmaf(w, Wf2[o * 2 + 0], a0);
            a1 = fmaf(w, Wf2[o * 2 + 1], a1);
        }
        G[i]        = a0;
        G[4096 + i] = a1;
        if (i < 2) {
            float s = bf2v[i];
            for (int o = 0; o < 64; o++) s = fmaf(bf1v[o], Wf2[o * 2 + i], s);
            c[i] = s;
        }
    } else {                              // F init with bias
        const int l = bid - 1104;         // 0..2047
        const int z = l >> 10;
        const float* bc = z ? bc2 : bc1;
        float*       f  = z ? f2  : f1;
        const int i = (l & 1023) * 256 + tid;
        const int c4 = (i & 15) * 4;
        float4 v = make_float4(bc[c4], bc[c4 + 1], bc[c4 + 2], bc[c4 + 3]);
        reinterpret_cast<float4*>(f)[i] = v;
    }
}

// ---------------------------------------------------------------------------
// GEMM1 fused, fp32-X input (conversion fused into A-staging):
//   256x256 tile, BK=64, 8 waves (2M x 4N), 2 phases/K-tile (row-halves).
//   A: reg-staged — global fp32 (pre-swizzled source, sch=(tid&7)^(srow&7))
//      -> 4x dwordx4 -> cvt -> 2x ds_write_b128 to lane-linear dest (tid*16;
//      wave writes 1024B contiguous = conflict-free). Read side unchanged.
//      Rolling 16-reg set: p0 writes A(kt+1)h0 / loads A(kt+1)h1;
//                          p1 writes A(kt+1)h1 / loads A(kt+2)h0.
//   B: gl2lds, units 0-1 issued @p0, units 2-3 @p1 (targets LDS[d^1]).
//   Waits: compiler inserts exact vmcnt(2) before each cvt; manual
//   vmcnt(4) ONLY at end-p1 (drains B(kt+1), keeps R in flight); end-p0
//   needs lgkmcnt(0) only. Tail loads clamped to tile 15 (in-bounds, dead).
// ---------------------------------------------------------------------------
__global__ __launch_bounds__(512, 2) void k_gemm1f(
    const float* __restrict__ X1, const float* __restrict__ X2,
    const bf16_t* __restrict__ WT1, const bf16_t* __restrict__ WT2,
    const float* __restrict__ bias1, const float* __restrict__ bias2,
    const bf16_t* __restrict__ WC1, const bf16_t* __restrict__ WC2,
    float* __restrict__ F1, float* __restrict__ F2)
{
    const int bid = blockIdx.x;
    const int nid = (bid & 7) * 32 + (bid >> 3);   // bijective: 256 = 8*32
    const int z   = nid >> 7;                      // branch
    const int nb  = (nid >> 6) & 1;                // N column tile
    const int mb  = nid & 63;                      // M tile

    const float*  X    = z ? X2    : X1;
    const bf16_t* WT   = z ? WT2   : WT1;
    const float*  bias = z ? bias2 : bias1;
    const bf16_t* WC   = z ? WC2   : WC1;
    float*        F    = z ? F2    : F1;

    const int m0 = mb * 256;
    const int n0 = nb * 256;

    // A slots at 0 / 32K (h0 = rows 0-127 at +0, h1 at +16K),
    // B slots at 64K / 96K. Epilogue Hs[256][264] aliases everything.
    __shared__ __align__(128) char smem[135168];

    const int tid  = threadIdx.x;
    const int lane = tid & 63;
    const int wave = tid >> 6;
    const int wm   = wave >> 2;      // 0..1
    const int wn   = wave & 3;       // 0..3
    const int l15  = lane & 15;
    const int g4   = lane >> 4;

    // ---- staging constants (64-row unit): row = u*64 + (tid>>3)
    const int srow = tid >> 3;                    // 0..63
    const int sch  = (tid & 7) ^ (srow & 7);      // swizzled source k-chunk
    const float*  gX = X  + (size_t)(m0 + srow) * DIN + sch * 8;
    const bf16_t* gB = WT + (size_t)(n0 + srow) * DIN + sch * 8;
    const int ldst = tid * 16;                    // lane-linear LDS dest

    // ---- fragment-read constants (row&7 == l15&7: row bases are mult of 8)
    const int l7   = l15 & 7;
    const int lch0 = (g4 ^ l7) * 16;              // k-chunks 0-3 (u=0)
    const int lch1 = ((4 + g4) ^ l7) * 16;        // k-chunks 4-7 (u=1)
    const int abase = (wm * 64 + l15) * 128;      // A row byte base in half
    const int bbase = (wn * 64 + l15) * 128;      // B row byte base

    f32x4 acc[2][4][4] = {};                      // [phase(row-half)][mi][ni]
    float4 r0, r1, r2, r3;                        // rolling A fp32 set (16 VGPR)

    // ---- prologue: B(0) via gl2lds; A(0) cvt'd in-register; A(1)h0 in flight
    #pragma unroll
    for (int u = 0; u < 4; u++)
        gl2lds16(gB + (size_t)u * 64 * DIN, smem + 65536 + u * 8192 + ldst);
    // A(0)h0
    r0 = *(const float4*)(gX);
    r1 = *(const float4*)(gX + 4);
    r2 = *(const float4*)(gX + (size_t)64 * DIN);
    r3 = *(const float4*)(gX + (size_t)64 * DIN + 4);
    *(bf16x8*)(smem + ldst)        = cvt8(r0, r1);
    *(bf16x8*)(smem + 8192 + ldst) = cvt8(r2, r3);
    // A(0)h1
    r0 = *(const float4*)(gX + (size_t)128 * DIN);
    r1 = *(const float4*)(gX + (size_t)128 * DIN + 4);
    r2 = *(const float4*)(gX + (size_t)192 * DIN);
    r3 = *(const float4*)(gX + (size_t)192 * DIN + 4);
    *(bf16x8*)(smem + 16384 + ldst)        = cvt8(r0, r1);
    *(bf16x8*)(smem + 16384 + 8192 + ldst) = cvt8(r2, r3);
    // A(1)h0 -> R (left in flight across the barrier)
    r0 = *(const float4*)(gX + 64);
    r1 = *(const float4*)(gX + 64 + 4);
    r2 = *(const float4*)(gX + (size_t)64 * DIN + 64);
    r3 = *(const float4*)(gX + (size_t)64 * DIN + 64 + 4);
    asm volatile("s_waitcnt lgkmcnt(0)" ::: "memory");
    __builtin_amdgcn_s_barrier();
    __builtin_amdgcn_sched_barrier(0);

    #pragma unroll 1
    for (int kt = 0; kt < 16; ++kt) {
        const int d = kt & 1;
        const char* Ac = smem + d * 32768;
        const char* Bc = smem + 65536 + d * 32768;
        char* An = (char*)smem + (d ^ 1) * 32768;
        char* Bn = (char*)smem + 65536 + (d ^ 1) * 32768;
        const int kb  = (kt < 15 ? kt + 1 : 15) * 64;   // B col (elems, clamped)
        const int kc1 = kb;                             // A h1 col (floats)
        const int kc2 = (kt < 14 ? kt + 2 : 15) * 64;   // A h0 next col

        // ================= phase 0: C rows 0-127 (A-h0 + all B)
        gl2lds16(gB + (size_t)0 * 64 * DIN + kb, Bn + 0 * 8192 + ldst);
        gl2lds16(gB + (size_t)1 * 64 * DIN + kb, Bn + 1 * 8192 + ldst);
        __builtin_amdgcn_sched_barrier(0);
        // cvt R (=A(kt+1)h0; compiler emits vmcnt(2)) -> LDS[d^1] h0
        *(bf16x8*)(An + ldst)        = cvt8(r0, r1);
        *(bf16x8*)(An + 8192 + ldst) = cvt8(r2, r3);
        __builtin_amdgcn_sched_barrier(0);
        // load R <- A(kt+1)h1
        r0 = *(const float4*)(gX + (size_t)128 * DIN + kc1);
        r1 = *(const float4*)(gX + (size_t)128 * DIN + kc1 + 4);
        r2 = *(const float4*)(gX + (size_t)192 * DIN + kc1);
        r3 = *(const float4*)(gX + (size_t)192 * DIN + kc1 + 4);
        __builtin_amdgcn_sched_barrier(0);

        bf16x8 a[4][2], b[4][2];
        #pragma unroll
        for (int mi = 0; mi < 4; mi++) {
            a[mi][0] = *(const bf16x8*)(Ac + abase + mi * 2048 + lch0);
            a[mi][1] = *(const bf16x8*)(Ac + abase + mi * 2048 + lch1);
        }
        #pragma unroll
        for (int ni = 0; ni < 4; ni++) {
            b[ni][0] = *(const bf16x8*)(Bc + bbase + ni * 2048 + lch0);
            b[ni][1] = *(const bf16x8*)(Bc + bbase + ni * 2048 + lch1);
        }
        __builtin_amdgcn_s_setprio(1);
        #pragma unroll
        for (int mi = 0; mi < 4; mi++)
            #pragma unroll
            for (int ni = 0; ni < 4; ni++) {
                acc[0][mi][ni] = MFMA16(a[mi][0], b[ni][0], acc[0][mi][ni], 0, 0, 0);
                acc[0][mi][ni] = MFMA16(a[mi][1], b[ni][1], acc[0][mi][ni], 0, 0, 0);
            }
        __builtin_amdgcn_s_setprio(0);
        __builtin_amdgcn_sched_barrier(0);
        asm volatile("s_waitcnt lgkmcnt(0)" ::: "memory");
        __builtin_amdgcn_s_barrier();
        __builtin_amdgcn_sched_barrier(0);

        // ================= phase 1: C rows 128-255 (A-h1; b frags live)
        gl2lds16(gB + (size_t)2 * 64 * DIN + kb, Bn + 2 * 8192 + ldst);
        gl2lds16(gB + (size_t)3 * 64 * DIN + kb, Bn + 3 * 8192 + ldst);
        __builtin_amdgcn_sched_barrier(0);
        // cvt R (=A(kt+1)h1; compiler emits vmcnt(2)) -> LDS[d^1] h1
        *(bf16x8*)(An + 16384 + ldst)        = cvt8(r0, r1);
        *(bf16x8*)(An + 16384 + 8192 + ldst) = cvt8(r2, r3);
        __builtin_amdgcn_sched_barrier(0);
        // load R <- A(kt+2)h0
        r0 = *(const float4*)(gX + kc2);
        r1 = *(const float4*)(gX + kc2 + 4);
        r2 = *(const float4*)(gX + (size_t)64 * DIN + kc2);
        r3 = *(const float4*)(gX + (size_t)64 * DIN + kc2 + 4);
        __builtin_amdgcn_sched_barrier(0);

        bf16x8 a2[4][2];
        #pragma unroll
        for (int mi = 0; mi < 4; mi++) {
            a2[mi][0] = *(const bf16x8*)(Ac + 16384 + abase + mi * 2048 + lch0);
            a2[mi][1] = *(const bf16x8*)(Ac + 16384 + abase + mi * 2048 + lch1);
        }
        __builtin_amdgcn_s_setprio(1);
        #pragma unroll
        for (int mi = 0; mi < 4; mi++)
            #pragma unroll
            for (int ni = 0; ni < 4; ni++) {
                acc[1][mi][ni] = MFMA16(a2[mi][0], b[ni][0], acc[1][mi][ni], 0, 0, 0);
                acc[1][mi][ni] = MFMA16(a2[mi][1], b[ni][1], acc[1][mi][ni], 0, 0, 0);
            }
        __builtin_amdgcn_s_setprio(0);
        __builtin_amdgcn_sched_barrier(0);
        // drain B(kt+1) (issued this tile); keep R (A(kt+2)h0) in flight
        asm volatile("s_waitcnt vmcnt(4) lgkmcnt(0)" ::: "memory");
        __builtin_amdgcn_s_barrier();
        __builtin_amdgcn_sched_barrier(0);
    }

    // drain stray tail loads before aliasing smem
    asm volatile("s_waitcnt vmcnt(0) lgkmcnt(0)" ::: "memory");
    __builtin_amdgcn_s_barrier();

    // ---- epilogue phase 1: Hs[256][264] = relu(H + bias)  (aliases smem)
    bf16_t* Hs = (bf16_t*)smem;
    float bv[4];
    #pragma unroll
    for (int ni = 0; ni < 4; ni++)
        bv[ni] = bias[n0 + wn * 64 + ni * 16 + l15];
    #pragma unroll
    for (int ph = 0; ph < 2; ph++) {
        #pragma unroll
        for (int mi = 0; mi < 4; mi++) {
            const int lr = ph * 128 + wm * 64 + mi * 16 + g4 * 4;
            #pragma unroll
            for (int ni = 0; ni < 4; ni++) {
                const int colL = wn * 64 + ni * 16 + l15;
                #pragma unroll
                for (int r = 0; r < 4; r++) {
                    float v = fmaxf(acc[ph][mi][ni][r] + bv[ni], 0.0f);
                    Hs[(lr + r) * 264 + colL] = (bf16_t)v;
                }
            }
        }
    }
    __syncthreads();

    // ---- epilogue phase 2: each wave F[32 rows][64] += Hs-slice @ wct
    f32x4 acc2[2][4] = {};
    #pragma unroll
    for (int kk = 0; kk < 256; kk += 32) {
        bf16x8 af2[2];
        #pragma unroll
        for (int m2 = 0; m2 < 2; m2++)
            af2[m2] = *(const bf16x8*)(Hs + (wave * 32 + m2 * 16 + l15) * 264 + kk + g4 * 8);
        #pragma unroll
        for (int ni = 0; ni < 4; ni++) {
            bf16x8 bw = *(const bf16x8*)(&WC[(size_t)(ni * 16 + l15) * HID + n0 + kk + g4 * 8]);
            #pragma unroll
            for (int m2 = 0; m2 < 2; m2++)
                acc2[m2][ni] = MFMA16(af2[m2], bw, acc2[m2][ni], 0, 0, 0);
        }
    }
    #pragma unroll
    for (int m2 = 0; m2 < 2; m2++) {
        const int rbase = m0 + wave * 32 + m2 * 16 + g4 * 4;
        #pragma unroll
        for (int ni = 0; ni < 4; ni++) {
            const int col = ni * 16 + l15;
            #pragma unroll
            for (int r = 0; r < 4; r++)
                unsafeAtomicAdd(&F[(size_t)(rbase + r) * COMP + col], acc2[m2][ni][r]);
        }
    }
}

// ---------------------------------------------------------------------------
// bilinear (fp32, G-broadcast form — unchanged from round 3):
//   out[b][j] = f2[b,:] . G_j . f1[b,:]^T + c[j]
// ---------------------------------------------------------------------------
__global__ __launch_bounds__(256) void k_bilinear(
    const float* __restrict__ f1, const float* __restrict__ f2,
    const float* __restrict__ G, const float* __restrict__ c,
    float* __restrict__ out)
{
    __shared__ float Gs[2][4096];
    __shared__ float f1t[64][66];
    __shared__ float f2t[64][66];
    __shared__ float part[4][64];

    const int tid = threadIdx.x;
    const int s0  = blockIdx.x * 64;

    for (int i = tid; i < 2048; i += 256)
        reinterpret_cast<float4*>(&Gs[0][0])[i] =
            reinterpret_cast<const float4*>(G)[i];

    #pragma unroll
    for (int rr = 0; rr < 4; rr++) {
        const int row = (tid >> 4) + rr * 16;     // sample within tile
        const int c4  = (tid & 15) * 4;
        float4 v1 = *reinterpret_cast<const float4*>(&f1[(size_t)(s0 + row) * 64 + c4]);
        float4 v2 = *reinterpret_cast<const float4*>(&f2[(size_t)(s0 + row) * 64 + c4]);
        f1t[c4 + 0][row] = v1.x; f1t[c4 + 1][row] = v1.y;
        f1t[c4 + 2][row] = v1.z; f1t[c4 + 3][row] = v1.w;
        f2t[c4 + 0][row] = v2.x; f2t[c4 + 1][row] = v2.y;
        f2t[c4 + 2][row] = v2.z; f2t[c4 + 3][row] = v2.w;
    }
    __syncthreads();

    const int lane = tid & 63;        // sample
    const int wv   = tid >> 6;        // 0..3
    const int j    = wv & 1;
    const int qh   = (wv >> 1) * 32;

    float tq[32];
    #pragma unroll
    for (int q = 0; q < 32; q++) tq[q] = 0.f;

    #pragma unroll 4
    for (int p = 0; p < 64; p++) {
        const float f2p = f2t[p][lane];
        const float* Gp = &Gs[j][p * 64 + qh];
        #pragma unroll
        for (int q4 = 0; q4 < 8; q4++) {
            float4 g = *reinterpret_cast<const float4*>(Gp + q4 * 4);
            tq[q4 * 4 + 0] = fmaf(f2p, g.x, tq[q4 * 4 + 0]);
            tq[q4 * 4 + 1] = fmaf(f2p, g.y, tq[q4 * 4 + 1]);
            tq[q4 * 4 + 2] = fmaf(f2p, g.z, tq[q4 * 4 + 2]);
            tq[q4 * 4 + 3] = fmaf(f2p, g.w, tq[q4 * 4 + 3]);
        }
    }

    float o = 0.f;
    #pragma unroll
    for (int q = 0; q < 32; q++)
        o = fmaf(f1t[qh + q][lane], tq[q], o);

    part[wv][lane] = o;
    __syncthreads();

    if (wv < 2) {
        float r = part[wv][lane] + part[wv + 2][lane] + c[wv];
        out[(size_t)(s0 + lane) * 2 + wv] = r;
    }
}

// ---------------------------------------------------------------------------
extern "C" void kernel_launch(void* const* d_in, const int* in_sizes, int n_in,
                              void* d_out, int out_size, void* d_ws, size_t ws_size,
                              hipStream_t stream)
{
    const float* x1  = (const float*)d_in[0];
    const float* x2  = (const float*)d_in[1];
    const float* Wb1 = (const float*)d_in[2];
    const float* bb1 = (const float*)d_in[3];
    const float* Wb2 = (const float*)d_in[4];
    const float* bb2 = (const float*)d_in[5];
    const float* Wc1 = (const float*)d_in[6];
    const float* bc1 = (const float*)d_in[7];
    const float* Wc2 = (const float*)d_in[8];
    const float* bc2 = (const float*)d_in[9];
    const float* Wf1 = (const float*)d_in[10];
    const float* bf1v = (const float*)d_in[11];
    const float* Wf2 = (const float*)d_in[12];
    const float* bf2v = (const float*)d_in[13];
    float* out = (float*)d_out;

    // workspace carve-up (~10.8 MB — xb buffers removed)
    char* ws = (char*)d_ws;
    bf16_t* wbt1 = (bf16_t*)ws; ws += (size_t)HID * DIN * 2;
    bf16_t* wbt2 = (bf16_t*)ws; ws += (size_t)HID * DIN * 2;
    bf16_t* wct1 = (bf16_t*)ws; ws += (size_t)COMP * HID * 2;
    bf16_t* wct2 = (bf16_t*)ws; ws += (size_t)COMP * HID * 2;
    float*  f1   = (float*)ws;  ws += (size_t)B_SZ * COMP * 4;
    float*  f2   = (float*)ws;  ws += (size_t)B_SZ * COMP * 4;
    float*  G    = (float*)ws;  ws += (size_t)2 * 4096 * 4;
    float*  c    = (float*)ws;  ws += 256;

    k_prep<<<3152, 256, 0, stream>>>(Wb1, Wb2, wbt1, wbt2,
                                     Wc1, Wc2, wct1, wct2,
                                     Wf1, bf1v, Wf2, bf2v,
                                     bc1, bc2, f1, f2, G, c);
    k_gemm1f<<<256, 512, 0, stream>>>(x1, x2, wbt1, wbt2, bb1, bb2,
                                      wct1, wct2, f1, f2);
    k_bilinear<<<256, 256, 0, stream>>>(f1, f2, G, c, out);
}

// Round 5
// 215.280 us; speedup vs baseline: 1.2197x; 1.0416x over previous
//
#include <hip/hip_runtime.h>

#define B_SZ 16384
#define DIN  1024
#define HID  512
#define COMP 64

typedef __bf16 bf16_t;
typedef __bf16 bf16x4 __attribute__((ext_vector_type(4)));
typedef __bf16 bf16x8 __attribute__((ext_vector_type(8)));
typedef float  f32x4  __attribute__((ext_vector_type(4)));

#define MFMA16 __builtin_amdgcn_mfma_f32_16x16x32_bf16

__device__ __forceinline__ void gl2lds16(const void* g, void* l) {
    __builtin_amdgcn_global_load_lds(
        (const __attribute__((address_space(1))) void*)g,
        (__attribute__((address_space(3))) void*)l, 16, 0, 0);
}

__device__ __forceinline__ bf16x8 cvt8(float4 a, float4 b) {
    bf16x8 o;
    o[0] = (bf16_t)a.x; o[1] = (bf16_t)a.y;
    o[2] = (bf16_t)a.z; o[3] = (bf16_t)a.w;
    o[4] = (bf16_t)b.x; o[5] = (bf16_t)b.y;
    o[6] = (bf16_t)b.z; o[7] = (bf16_t)b.w;
    return o;
}

// ---------------------------------------------------------------------------
// prep (unchanged from round 4):
//   [0,1024)      : Wb transpose -> bf16 [512][1024]  (x2 branches)
//   [1024,1088)   : Wc transpose -> bf16 [64][512]    (x2 branches)
//   [1088,1104)   : prepG
//   [1104,3152)   : init f1/f2 with bias bc (atomic accumulation target)
// ---------------------------------------------------------------------------
__global__ __launch_bounds__(256) void k_prep(
    const float* __restrict__ Wb1, const float* __restrict__ Wb2,
    bf16_t* __restrict__ wbt1, bf16_t* __restrict__ wbt2,
    const float* __restrict__ Wc1, const float* __restrict__ Wc2,
    bf16_t* __restrict__ wct1, bf16_t* __restrict__ wct2,
    const float* __restrict__ Wf1, const float* __restrict__ bf1v,
    const float* __restrict__ Wf2, const float* __restrict__ bf2v,
    const float* __restrict__ bc1, const float* __restrict__ bc2,
    float* __restrict__ f1, float* __restrict__ f2,
    float* __restrict__ G, float* __restrict__ c)
{
    const int bid = blockIdx.x, tid = threadIdx.x;

    __shared__ float tile[32][33];
    const int tx = tid & 31, ty = tid >> 5;

    if (bid < 1024) {                     // Wb transpose: K=1024, N=512
        const int z = bid >> 9, t = bid & 511;
        const float* in  = z ? Wb2  : Wb1;
        bf16_t*      out = z ? wbt2 : wbt1;
        const int n0 = (t & 15) * 32, k0 = (t >> 4) * 32;
        #pragma unroll
        for (int i = 0; i < 4; i++)
            tile[ty + i * 8][tx] = in[(size_t)(k0 + ty + i * 8) * HID + n0 + tx];
        __syncthreads();
        #pragma unroll
        for (int i = 0; i < 4; i++)
            out[(size_t)(n0 + ty + i * 8) * DIN + k0 + tx] = (bf16_t)tile[tx][ty + i * 8];
    } else if (bid < 1088) {              // Wc transpose: K=512, N=64
        const int l = bid - 1024;
        const int z = l >> 5, t = l & 31;
        const float* in  = z ? Wc2  : Wc1;
        bf16_t*      out = z ? wct2 : wct1;
        const int n0 = (t & 1) * 32, k0 = (t >> 1) * 32;
        #pragma unroll
        for (int i = 0; i < 4; i++)
            tile[ty + i * 8][tx] = in[(size_t)(k0 + ty + i * 8) * COMP + n0 + tx];
        __syncthreads();
        #pragma unroll
        for (int i = 0; i < 4; i++)
            out[(size_t)(n0 + ty + i * 8) * HID + k0 + tx] = (bf16_t)tile[tx][ty + i * 8];
    } else if (bid < 1104) {              // prepG
        const int i = (bid - 1088) * 256 + tid;   // 0..4095
        float a0 = 0.f, a1 = 0.f;
        #pragma unroll 8
        for (int o = 0; o < 64; o++) {
            float w = Wf1[(size_t)i * 64 + o];
            a0 = fmaf(w, Wf2[o * 2 + 0], a0);
            a1 = fmaf(w, Wf2[o * 2 + 1], a1);
        }
        G[i]        = a0;
        G[4096 + i] = a1;
        if (i < 2) {
            float s = bf2v[i];
            for (int o = 0; o < 64; o++) s = fmaf(bf1v[o], Wf2[o * 2 + i], s);
            c[i] = s;
        }
    } else {                              // F init with bias
        const int l = bid - 1104;         // 0..2047
        const int z = l >> 10;
        const float* bc = z ? bc2 : bc1;
        float*       f  = z ? f2  : f1;
        const int i = (l & 1023) * 256 + tid;
        const int c4 = (i & 15) * 4;
        float4 v = make_float4(bc[c4], bc[c4 + 1], bc[c4 + 2], bc[c4 + 3]);
        reinterpret_cast<float4*>(f)[i] = v;
    }
}

// ---------------------------------------------------------------------------
// GEMM1 fused, fp32-X input, SINGLE-BARRIER tile (merged phases):
//   256x256 tile, BK=64, 8 waves (2M x 4N). Hazard audit: one end-of-tile
//   {vmcnt(4) lgkmcnt(0); s_barrier} covers all cross-tile LDS hazards
//   (each wave's reads drain before its own barrier; next tile's writes
//   begin only after). Mid-tile barrier REMOVED -> waves skew within a
//   tile, overlapping one wave's MFMA with another's ds_reads (LDS-port
//   bound kernel: ~192 b128 frag reads/CU/tile vs ~2480 cyc MFMA).
//   Tile order: compute-h0 | cvt-write A(kt+1)h0 | R<-A(kt+1)h1 |
//   B(kt+1) gl2lds | compute-h1 | cvt-write h1 | R<-A(kt+2)h0 | waits+bar.
//   VM issue order pinned (R4,B4,R4) so manual vmcnt(4) drains exactly B.
// ---------------------------------------------------------------------------
__global__ __launch_bounds__(512, 2) void k_gemm1f(
    const float* __restrict__ X1, const float* __restrict__ X2,
    const bf16_t* __restrict__ WT1, const bf16_t* __restrict__ WT2,
    const float* __restrict__ bias1, const float* __restrict__ bias2,
    const bf16_t* __restrict__ WC1, const bf16_t* __restrict__ WC2,
    float* __restrict__ F1, float* __restrict__ F2)
{
    const int bid = blockIdx.x;
    const int nid = (bid & 7) * 32 + (bid >> 3);   // bijective: 256 = 8*32
    const int z   = nid >> 7;                      // branch
    const int nb  = (nid >> 6) & 1;                // N column tile
    const int mb  = nid & 63;                      // M tile

    const float*  X    = z ? X2    : X1;
    const bf16_t* WT   = z ? WT2   : WT1;
    const float*  bias = z ? bias2 : bias1;
    const bf16_t* WC   = z ? WC2   : WC1;
    float*        F    = z ? F2    : F1;

    const int m0 = mb * 256;
    const int n0 = nb * 256;

    // A slots at 0 / 32K (h0 = rows 0-127 at +0, h1 at +16K),
    // B slots at 64K / 96K. Epilogue Hs[256][264] aliases everything.
    __shared__ __align__(128) char smem[135168];

    const int tid  = threadIdx.x;
    const int lane = tid & 63;
    const int wave = tid >> 6;
    const int wm   = wave >> 2;      // 0..1
    const int wn   = wave & 3;       // 0..3
    const int l15  = lane & 15;
    const int g4   = lane >> 4;

    // ---- staging constants (64-row unit): row = u*64 + (tid>>3)
    const int srow = tid >> 3;                    // 0..63
    const int sch  = (tid & 7) ^ (srow & 7);      // swizzled source k-chunk
    const float*  gX = X  + (size_t)(m0 + srow) * DIN + sch * 8;
    const bf16_t* gB = WT + (size_t)(n0 + srow) * DIN + sch * 8;
    const int ldst = tid * 16;                    // lane-linear LDS dest

    // ---- fragment-read constants (row&7 == l15&7: row bases are mult of 8)
    const int l7   = l15 & 7;
    const int lch0 = (g4 ^ l7) * 16;              // k-chunks 0-3 (u=0)
    const int lch1 = ((4 + g4) ^ l7) * 16;        // k-chunks 4-7 (u=1)
    const int abase = (wm * 64 + l15) * 128;      // A row byte base in half
    const int bbase = (wn * 64 + l15) * 128;      // B row byte base

    f32x4 acc[2][4][4] = {};                      // [row-half][mi][ni]
    float4 r0, r1, r2, r3;                        // rolling A fp32 set (16 VGPR)

    // ---- prologue: B(0) gl2lds; A(0) direct cvt; R <- A(1)h0 in flight
    #pragma unroll
    for (int u = 0; u < 4; u++)
        gl2lds16(gB + (size_t)u * 64 * DIN, smem + 65536 + u * 8192 + ldst);
    // A(0)h0
    r0 = *(const float4*)(gX);
    r1 = *(const float4*)(gX + 4);
    r2 = *(const float4*)(gX + (size_t)64 * DIN);
    r3 = *(const float4*)(gX + (size_t)64 * DIN + 4);
    *(bf16x8*)(smem + ldst)        = cvt8(r0, r1);
    *(bf16x8*)(smem + 8192 + ldst) = cvt8(r2, r3);
    // A(0)h1
    r0 = *(const float4*)(gX + (size_t)128 * DIN);
    r1 = *(const float4*)(gX + (size_t)128 * DIN + 4);
    r2 = *(const float4*)(gX + (size_t)192 * DIN);
    r3 = *(const float4*)(gX + (size_t)192 * DIN + 4);
    *(bf16x8*)(smem + 16384 + ldst)        = cvt8(r0, r1);
    *(bf16x8*)(smem + 16384 + 8192 + ldst) = cvt8(r2, r3);
    // R <- A(1)h0 (left in flight across the barrier)
    r0 = *(const float4*)(gX + 64);
    r1 = *(const float4*)(gX + 64 + 4);
    r2 = *(const float4*)(gX + (size_t)64 * DIN + 64);
    r3 = *(const float4*)(gX + (size_t)64 * DIN + 64 + 4);
    __builtin_amdgcn_sched_barrier(0);
    asm volatile("s_waitcnt vmcnt(4) lgkmcnt(0)" ::: "memory");  // drain B(0); keep R
    __builtin_amdgcn_s_barrier();
    __builtin_amdgcn_sched_barrier(0);

    #pragma unroll 1
    for (int kt = 0; kt < 16; ++kt) {
        const int d = kt & 1;
        const char* Ac = smem + d * 32768;
        const char* Bc = smem + 65536 + d * 32768;
        char* An = (char*)smem + (d ^ 1) * 32768;
        char* Bn = (char*)smem + 65536 + (d ^ 1) * 32768;
        const int kc1 = (kt < 15 ? kt + 1 : 15) * 64;   // A-h1 / B col (clamped)
        const int kc2 = (kt < 14 ? kt + 2 : 15) * 64;   // next A-h0 col

        // ---- compute h0: frag reads (a-h0 + all b) + 32 MFMA
        bf16x8 a[4][2], b[4][2];
        #pragma unroll
        for (int mi = 0; mi < 4; mi++) {
            a[mi][0] = *(const bf16x8*)(Ac + abase + mi * 2048 + lch0);
            a[mi][1] = *(const bf16x8*)(Ac + abase + mi * 2048 + lch1);
        }
        #pragma unroll
        for (int ni = 0; ni < 4; ni++) {
            b[ni][0] = *(const bf16x8*)(Bc + bbase + ni * 2048 + lch0);
            b[ni][1] = *(const bf16x8*)(Bc + bbase + ni * 2048 + lch1);
        }
        __builtin_amdgcn_s_setprio(1);
        #pragma unroll
        for (int mi = 0; mi < 4; mi++)
            #pragma unroll
            for (int ni = 0; ni < 4; ni++) {
                acc[0][mi][ni] = MFMA16(a[mi][0], b[ni][0], acc[0][mi][ni], 0, 0, 0);
                acc[0][mi][ni] = MFMA16(a[mi][1], b[ni][1], acc[0][mi][ni], 0, 0, 0);
            }
        __builtin_amdgcn_s_setprio(0);
        __builtin_amdgcn_sched_barrier(0);

        // ---- cvt-write A(kt+1)h0 (R loaded last tile; compiler-counted wait)
        *(bf16x8*)(An + ldst)        = cvt8(r0, r1);
        *(bf16x8*)(An + 8192 + ldst) = cvt8(r2, r3);
        __builtin_amdgcn_sched_barrier(0);
        // ---- R <- A(kt+1)h1
        r0 = *(const float4*)(gX + (size_t)128 * DIN + kc1);
        r1 = *(const float4*)(gX + (size_t)128 * DIN + kc1 + 4);
        r2 = *(const float4*)(gX + (size_t)192 * DIN + kc1);
        r3 = *(const float4*)(gX + (size_t)192 * DIN + kc1 + 4);
        __builtin_amdgcn_sched_barrier(0);
        // ---- B(kt+1) -> Bn
        gl2lds16(gB + (size_t)0 * 64 * DIN + kc1, Bn + 0 * 8192 + ldst);
        gl2lds16(gB + (size_t)1 * 64 * DIN + kc1, Bn + 1 * 8192 + ldst);
        gl2lds16(gB + (size_t)2 * 64 * DIN + kc1, Bn + 2 * 8192 + ldst);
        gl2lds16(gB + (size_t)3 * 64 * DIN + kc1, Bn + 3 * 8192 + ldst);
        __builtin_amdgcn_sched_barrier(0);

        // ---- compute h1: frag reads (a-h1; b live in regs) + 32 MFMA
        bf16x8 a2[4][2];
        #pragma unroll
        for (int mi = 0; mi < 4; mi++) {
            a2[mi][0] = *(const bf16x8*)(Ac + 16384 + abase + mi * 2048 + lch0);
            a2[mi][1] = *(const bf16x8*)(Ac + 16384 + abase + mi * 2048 + lch1);
        }
        __builtin_amdgcn_s_setprio(1);
        #pragma unroll
        for (int mi = 0; mi < 4; mi++)
            #pragma unroll
            for (int ni = 0; ni < 4; ni++) {
                acc[1][mi][ni] = MFMA16(a2[mi][0], b[ni][0], acc[1][mi][ni], 0, 0, 0);
                acc[1][mi][ni] = MFMA16(a2[mi][1], b[ni][1], acc[1][mi][ni], 0, 0, 0);
            }
        __builtin_amdgcn_s_setprio(0);
        __builtin_amdgcn_sched_barrier(0);

        // ---- cvt-write A(kt+1)h1 (consumes R from this tile's h1 load)
        *(bf16x8*)(An + 16384 + ldst)        = cvt8(r0, r1);
        *(bf16x8*)(An + 16384 + 8192 + ldst) = cvt8(r2, r3);
        __builtin_amdgcn_sched_barrier(0);
        // ---- R <- A(kt+2)h0
        r0 = *(const float4*)(gX + kc2);
        r1 = *(const float4*)(gX + kc2 + 4);
        r2 = *(const float4*)(gX + (size_t)64 * DIN + kc2);
        r3 = *(const float4*)(gX + (size_t)64 * DIN + kc2 + 4);
        __builtin_amdgcn_sched_barrier(0);

        // ---- single end-of-tile sync: drain B(kt+1) + all DS; keep R
        asm volatile("s_waitcnt vmcnt(4) lgkmcnt(0)" ::: "memory");
        __builtin_amdgcn_s_barrier();
        __builtin_amdgcn_sched_barrier(0);
    }

    // drain stray tail loads before aliasing smem
    asm volatile("s_waitcnt vmcnt(0) lgkmcnt(0)" ::: "memory");
    __builtin_amdgcn_s_barrier();

    // ---- epilogue phase 1: Hs[256][264] = relu(H + bias)  (aliases smem)
    bf16_t* Hs = (bf16_t*)smem;
    float bv[4];
    #pragma unroll
    for (int ni = 0; ni < 4; ni++)
        bv[ni] = bias[n0 + wn * 64 + ni * 16 + l15];
    #pragma unroll
    for (int ph = 0; ph < 2; ph++) {
        #pragma unroll
        for (int mi = 0; mi < 4; mi++) {
            const int lr = ph * 128 + wm * 64 + mi * 16 + g4 * 4;
            #pragma unroll
            for (int ni = 0; ni < 4; ni++) {
                const int colL = wn * 64 + ni * 16 + l15;
                #pragma unroll
                for (int r = 0; r < 4; r++) {
                    float v = fmaxf(acc[ph][mi][ni][r] + bv[ni], 0.0f);
                    Hs[(lr + r) * 264 + colL] = (bf16_t)v;
                }
            }
        }
    }
    __syncthreads();

    // ---- epilogue phase 2: each wave F[32 rows][64] += Hs-slice @ wct
    f32x4 acc2[2][4] = {};
    #pragma unroll
    for (int kk = 0; kk < 256; kk += 32) {
        bf16x8 af2[2];
        #pragma unroll
        for (int m2 = 0; m2 < 2; m2++)
            af2[m2] = *(const bf16x8*)(Hs + (wave * 32 + m2 * 16 + l15) * 264 + kk + g4 * 8);
        #pragma unroll
        for (int ni = 0; ni < 4; ni++) {
            bf16x8 bw = *(const bf16x8*)(&WC[(size_t)(ni * 16 + l15) * HID + n0 + kk + g4 * 8]);
            #pragma unroll
            for (int m2 = 0; m2 < 2; m2++)
                acc2[m2][ni] = MFMA16(af2[m2], bw, acc2[m2][ni], 0, 0, 0);
        }
    }
    #pragma unroll
    for (int m2 = 0; m2 < 2; m2++) {
        const int rbase = m0 + wave * 32 + m2 * 16 + g4 * 4;
        #pragma unroll
        for (int ni = 0; ni < 4; ni++) {
            const int col = ni * 16 + l15;
            #pragma unroll
            for (int r = 0; r < 4; r++)
                unsafeAtomicAdd(&F[(size_t)(rbase + r) * COMP + col], acc2[m2][ni][r]);
        }
    }
}

// ---------------------------------------------------------------------------
// bilinear (fp32, G-broadcast form — unchanged from round 4):
//   out[b][j] = f2[b,:] . G_j . f1[b,:]^T + c[j]
// ---------------------------------------------------------------------------
__global__ __launch_bounds__(256) void k_bilinear(
    const float* __restrict__ f1, const float* __restrict__ f2,
    const float* __restrict__ G, const float* __restrict__ c,
    float* __restrict__ out)
{
    __shared__ float Gs[2][4096];
    __shared__ float f1t[64][66];
    __shared__ float f2t[64][66];
    __shared__ float part[4][64];

    const int tid = threadIdx.x;
    const int s0  = blockIdx.x * 64;

    for (int i = tid; i < 2048; i += 256)
        reinterpret_cast<float4*>(&Gs[0][0])[i] =
            reinterpret_cast<const float4*>(G)[i];

    #pragma unroll
    for (int rr = 0; rr < 4; rr++) {
        const int row = (tid >> 4) + rr * 16;     // sample within tile
        const int c4  = (tid & 15) * 4;
        float4 v1 = *reinterpret_cast<const float4*>(&f1[(size_t)(s0 + row) * 64 + c4]);
        float4 v2 = *reinterpret_cast<const float4*>(&f2[(size_t)(s0 + row) * 64 + c4]);
        f1t[c4 + 0][row] = v1.x; f1t[c4 + 1][row] = v1.y;
        f1t[c4 + 2][row] = v1.z; f1t[c4 + 3][row] = v1.w;
        f2t[c4 + 0][row] = v2.x; f2t[c4 + 1][row] = v2.y;
        f2t[c4 + 2][row] = v2.z; f2t[c4 + 3][row] = v2.w;
    }
    __syncthreads();

    const int lane = tid & 63;        // sample
    const int wv   = tid >> 6;        // 0..3
    const int j    = wv & 1;
    const int qh   = (wv >> 1) * 32;

    float tq[32];
    #pragma unroll
    for (int q = 0; q < 32; q++) tq[q] = 0.f;

    #pragma unroll 4
    for (int p = 0; p < 64; p++) {
        const float f2p = f2t[p][lane];
        const float* Gp = &Gs[j][p * 64 + qh];
        #pragma unroll
        for (int q4 = 0; q4 < 8; q4++) {
            float4 g = *reinterpret_cast<const float4*>(Gp + q4 * 4);
            tq[q4 * 4 + 0] = fmaf(f2p, g.x, tq[q4 * 4 + 0]);
            tq[q4 * 4 + 1] = fmaf(f2p, g.y, tq[q4 * 4 + 1]);
            tq[q4 * 4 + 2] = fmaf(f2p, g.z, tq[q4 * 4 + 2]);
            tq[q4 * 4 + 3] = fmaf(f2p, g.w, tq[q4 * 4 + 3]);
        }
    }

    float o = 0.f;
    #pragma unroll
    for (int q = 0; q < 32; q++)
        o = fmaf(f1t[qh + q][lane], tq[q], o);

    part[wv][lane] = o;
    __syncthreads();

    if (wv < 2) {
        float r = part[wv][lane] + part[wv + 2][lane] + c[wv];
        out[(size_t)(s0 + lane) * 2 + wv] = r;
    }
}

// ---------------------------------------------------------------------------
extern "C" void kernel_launch(void* const* d_in, const int* in_sizes, int n_in,
                              void* d_out, int out_size, void* d_ws, size_t ws_size,
                              hipStream_t stream)
{
    const float* x1  = (const float*)d_in[0];
    const float* x2  = (const float*)d_in[1];
    const float* Wb1 = (const float*)d_in[2];
    const float* bb1 = (const float*)d_in[3];
    const float* Wb2 = (const float*)d_in[4];
    const float* bb2 = (const float*)d_in[5];
    const float* Wc1 = (const float*)d_in[6];
    const float* bc1 = (const float*)d_in[7];
    const float* Wc2 = (const float*)d_in[8];
    const float* bc2 = (const float*)d_in[9];
    const float* Wf1 = (const float*)d_in[10];
    const float* bf1v = (const float*)d_in[11];
    const float* Wf2 = (const float*)d_in[12];
    const float* bf2v = (const float*)d_in[13];
    float* out = (float*)d_out;

    // workspace carve-up (~10.8 MB)
    char* ws = (char*)d_ws;
    bf16_t* wbt1 = (bf16_t*)ws; ws += (size_t)HID * DIN * 2;
    bf16_t* wbt2 = (bf16_t*)ws; ws += (size_t)HID * DIN * 2;
    bf16_t* wct1 = (bf16_t*)ws; ws += (size_t)COMP * HID * 2;
    bf16_t* wct2 = (bf16_t*)ws; ws += (size_t)COMP * HID * 2;
    float*  f1   = (float*)ws;  ws += (size_t)B_SZ * COMP * 4;
    float*  f2   = (float*)ws;  ws += (size_t)B_SZ * COMP * 4;
    float*  G    = (float*)ws;  ws += (size_t)2 * 4096 * 4;
    float*  c    = (float*)ws;  ws += 256;

    k_prep<<<3152, 256, 0, stream>>>(Wb1, Wb2, wbt1, wbt2,
                                     Wc1, Wc2, wct1, wct2,
                                     Wf1, bf1v, Wf2, bf2v,
                                     bc1, bc2, f1, f2, G, c);
    k_gemm1f<<<256, 512, 0, stream>>>(x1, x2, wbt1, wbt2, bb1, bb2,
                                      wct1, wct2, f1, f2);
    k_bilinear<<<256, 256, 0, stream>>>(f1, f2, G, c, out);
}